// Round 12
// baseline (416.488 us; speedup 1.0000x reference)
//
#include <hip/hip_runtime.h>
#include <hip/hip_bf16.h>

// LiteMSA pipeline, MI355X gfx950.
// B=16, Cin=256, Cqkv=768, H=W=64 (P=4096), heads=64 (24 ch: q8,k8,v8),
// out 512 ch -> proj 256 ch + BN. Output y fp32.
//
// v11 = v10 + ATTN FUSED INTO GEMM_PROJ: proj computes its B-operand
// (attn out, bf16) on the fly from q + kv (bitwise-identical math), so
// attn_out kernel and its 167MB of traffic are gone (-134MB net).
// kvbuf (288K) relocated to DEAD qkv_bf b0 q-planes (dwpw was last reader);
// Awp (256K) to DEAD qkv_bf b0 k/v-planes ch8-23/32-47 (kv was last reader).
// Launch order guarantees: dwpw < kv (kvbuf write), kv < conv_wp (Awp write),
// conv_wp < proj. Numerics bitwise unchanged.
//
// ws (256 MiB):
//   qkv_bf [0,96M)    bf16 768ch; after kv: b0 q-planes hold kvbuf,
//                     b0 ch8-23/32-47 hold Awp
//   qplane [96M,160M) fp32 256ch (q of heads 0-31) — read by fused proj
//   agg_bf [160M,256M) bf16 768ch; ALIASED before dwpw by XTh/XTl/Awh/Awl
// d_out: qmeta (cnt + worklist) at +512K; y overwrites all at the end.

#define NB 16
#define CQKV 768
#define P4096 4096
#define QFIX_CAP (1u << 21)

typedef __bf16 bf16x8 __attribute__((ext_vector_type(8)));
typedef float f32x4 __attribute__((ext_vector_type(4)));

#define MFMA_BF16 __builtin_amdgcn_mfma_f32_16x16x32_bf16

__device__ __forceinline__ ushort f2bf(float f) {
    union { float f; unsigned int u; } x; x.f = f;
    unsigned int u = x.u;
    unsigned int r = (u + 0x7FFFu + ((u >> 16) & 1u)) >> 16;
    return (ushort)r;
}
__device__ __forceinline__ float bf2f(ushort u) {
    union { unsigned int u; float f; } x; x.u = ((unsigned int)u) << 16;
    return x.f;
}
__device__ __forceinline__ unsigned int pk2bf(float x, float y) {
    __hip_bfloat162 h = __float22bfloat162_rn(make_float2(x, y));  // v_cvt_pk_bf16_f32 (RNE)
    union { __hip_bfloat162 b; unsigned int u; } c; c.b = h; return c.u;
}

__device__ __forceinline__ void gload16(void* lds, const void* g) {
    __builtin_amdgcn_global_load_lds(
        (const __attribute__((address_space(1))) void*)g,
        (__attribute__((address_space(3))) void*)lds, 16, 0, 0);
}

// kvbuf linear float idx -> address in qkv_bf b0 q-planes (ch%24<8, dead
// after dwpw). plane p (8KB each) -> channel (p/8)*24 + p%8. 36 planes used.
__device__ __forceinline__ float* kvslot(const ushort* qkv, unsigned int f) {
    unsigned int byte = f * 4u;
    unsigned int plane = byte >> 13, within = byte & 8191u;
    unsigned int ch = (plane >> 3) * 24u + (plane & 7u);
    return (float*)((char*)qkv + ((size_t)ch << 13) + within);
}

// ---------------- conv_w: w_qkv -> virt-row-ordered, swizzled bf16 hi/lo (+ zero qmeta) ----------------
// virt rows: 0..255 q (phys=(v>>3)*24+v&7), 256..767 kv (phys=(v2>>4)*24+8+v2&15).
__global__ __launch_bounds__(128) void conv_w(
    const float* __restrict__ W, ushort* __restrict__ Ah, ushort* __restrict__ Al,
    unsigned int* __restrict__ qmeta)
{
    const int rv = blockIdx.x;     // 0..767
    const int t  = threadIdx.x;    // 0..127 -> c pair
    if (rv == 0 && t == 0) qmeta[0] = 0;
    int phys;
    if (rv < 256) phys = (rv >> 3) * 24 + (rv & 7);
    else { int r2 = rv - 256; phys = (r2 >> 4) * 24 + 8 + (r2 & 15); }
    int c = t * 2;
    float w0 = W[(size_t)phys * 256 + c];
    float w1 = W[(size_t)phys * 256 + c + 1];
    unsigned int h = pk2bf(w0, w1);
    float f0 = __uint_as_float(h << 16);
    float f1 = __uint_as_float(h & 0xffff0000u);
    unsigned int l = pk2bf(w0 - f0, w1 - f1);
    int sl = ((c >> 3) & 3) ^ ((rv >> 1) & 3);
    int idx = (c & ~31) + sl * 8 + (c & 7);
    *(unsigned int*)&Ah[(size_t)rv * 256 + idx] = h;
    *(unsigned int*)&Al[(size_t)rv * 256 + idx] = l;
}

// ---------------- conv_wp: w_proj 256x512 -> swizzled bf16, into qkv dead k/v planes ----------------
// row m<128 -> qkv b0 ch8..24 region; m>=128 -> ch32..48. Runs AFTER kv_kernel.
__global__ __launch_bounds__(256) void conv_wp(
    const float* __restrict__ W, ushort* __restrict__ qkvbuf)
{
    const int m = blockIdx.x;      // 0..255
    const int t = threadIdx.x;     // 0..255 -> c pair
    int c = t * 2;
    float w0 = W[(size_t)m * 512 + c];
    float w1 = W[(size_t)m * 512 + c + 1];
    unsigned int h = pk2bf(w0, w1);
    int sl = ((c >> 3) & 3) ^ ((m >> 1) & 3);
    int idx = (c & ~31) + sl * 8 + (c & 7);
    ushort* dst = qkvbuf + (m >= 128 ? (size_t)32 * 4096 + (size_t)(m - 128) * 512
                                     : (size_t)8 * 4096 + (size_t)m * 512);
    *(unsigned int*)&dst[idx] = h;
}

// ---------------- conv_x: x [b][256][4096] f32 -> XT hi/lo [b][4096][256] bf16, swizzled ----------------
__global__ __launch_bounds__(256) void conv_x(
    const float* __restrict__ X, ushort* __restrict__ XTh, ushort* __restrict__ XTl)
{
    const int pt = blockIdx.x;        // 0..63
    const int ct = blockIdx.y;        // 0..3
    const int b  = blockIdx.z;
    const int t  = threadIdx.x;
    const int p0 = pt * 64, c0 = ct * 64;

    __shared__ float tile[64][65];

    {
        int cr = t >> 2, pc = (t & 3) * 16;
        const float* xr = X + ((size_t)b * 256 + c0 + cr) * P4096 + p0 + pc;
        float4 v0 = *(const float4*)xr;
        float4 v1 = *(const float4*)(xr + 4);
        float4 v2 = *(const float4*)(xr + 8);
        float4 v3 = *(const float4*)(xr + 12);
        float* d = &tile[cr][pc];
        d[0]=v0.x; d[1]=v0.y; d[2]=v0.z; d[3]=v0.w;
        d[4]=v1.x; d[5]=v1.y; d[6]=v1.z; d[7]=v1.w;
        d[8]=v2.x; d[9]=v2.y; d[10]=v2.z; d[11]=v2.w;
        d[12]=v3.x; d[13]=v3.y; d[14]=v3.z; d[15]=v3.w;
    }
    __syncthreads();

    #pragma unroll
    for (int pass = 0; pass < 2; pass++) {
        int tp = t >> 2;
        int cc = (t & 3) + pass * 4;      // 0..7 chunk of 8 c
        int p  = p0 + tp;
        float v[8];
        #pragma unroll
        for (int j = 0; j < 8; j++) v[j] = tile[cc * 8 + j][tp];
        union { unsigned int u[4]; uint4 q; } H, L;
        #pragma unroll
        for (int i = 0; i < 4; i++) {
            unsigned int h = pk2bf(v[2 * i], v[2 * i + 1]);
            H.u[i] = h;
            float f0 = __uint_as_float(h << 16);
            float f1 = __uint_as_float(h & 0xffff0000u);
            L.u[i] = pk2bf(v[2 * i] - f0, v[2 * i + 1] - f1);
        }
        int c = c0 + cc * 8;
        int sl = ((c >> 3) & 3) ^ ((p >> 1) & 3);
        size_t idx = ((size_t)b * P4096 + p) * 256 + (c & ~31) + sl * 8;
        *(uint4*)&XTh[idx] = H.q;
        *(uint4*)&XTl[idx] = L.q;
    }
}

// ---------------- gemm_fused: all 768 virt rows; q tiles 3-term, kv tiles 1-term ----------------
// 128x128 tile, BK=32, 4 waves (2x2), 48KB LDS -> 3 blocks/CU.
// q branch: A (L2-hot) single-buffered, B double-buffered.
// kv branch: 3-stage pipeline, counted vmcnt(8).
// Grid 3072, XCD swizzle. q epilogue emits sparse qfix worklist.
__global__ __launch_bounds__(256, 3) void gemm_fused(
    const ushort* __restrict__ Ah, const ushort* __restrict__ Al,
    const ushort* __restrict__ Bh, const ushort* __restrict__ Bl,
    ushort* __restrict__ Cbf, float* __restrict__ qplane,
    unsigned int* __restrict__ qmeta)
{
    const int hw = blockIdx.x;                 // 0..3071
    const int lg = (hw & 7) * 384 + (hw >> 3); // XCD-contiguous logical id
    const int mt = lg % 6;
    const int rem = lg / 6;                    // 0..511
    const int n0 = (rem & 31) * 128;
    const int b  = rem >> 5;
    const int t  = threadIdx.x;
    const int wave = t >> 6, lane = t & 63, quad = lane >> 4, l15 = lane & 15;
    const int wr = wave >> 1, wc = wave & 1;
    const int M0 = mt * 128;

    __shared__ __align__(16) char smem[49152];   // 48 KB

    int aoff[4], boff[4];
    #pragma unroll
    for (int i = 0; i < 4; i++) {
        int ra = wr * 64 + i * 16 + l15;
        aoff[i] = ra * 64 + ((quad ^ ((ra >> 1) & 3)) << 4);
        int rb = wc * 64 + i * 16 + l15;
        boff[i] = rb * 64 + ((quad ^ ((rb >> 1) & 3)) << 4);
    }

    const int srow = t >> 2;               // 0..63
    const int schunk = (t & 3) * 8;        // ushort offset in 32-ushort window
    const size_t abase = (size_t)(M0 + srow) * 256 + schunk;
    const size_t bbase = ((size_t)b * P4096 + n0 + srow) * 256 + schunk;
    const int ldsoff = wave * 1024;        // bytes; +i*4096

    f32x4 acc[4][4];
    #pragma unroll
    for (int mi = 0; mi < 4; mi++)
        #pragma unroll
        for (int nj = 0; nj < 4; nj++)
            #pragma unroll
            for (int r = 0; r < 4; r++) acc[mi][nj][r] = 0.0f;

    if (mt < 2) {
        // ---- q rows: 3-term split; single-A (16K) + double-B (32K) ----
        char* AsH = smem;                  // 8K
        char* AsL = smem + 8192;           // 8K
        char* BsH[2] = { smem + 16384, smem + 24576 };
        char* BsL[2] = { smem + 32768, smem + 40960 };

        auto stageA = [&](int kw) {
            #pragma unroll
            for (int i = 0; i < 2; i++) {
                int lo = ldsoff + i * 4096;
                size_t so = (size_t)(i * 64) * 256 + (size_t)kw * 32;
                gload16(AsH + lo, Ah + abase + so);
                gload16(AsL + lo, Al + abase + so);
            }
        };
        auto stageB = [&](int d, int kw) {
            #pragma unroll
            for (int i = 0; i < 2; i++) {
                int lo = ldsoff + i * 4096;
                size_t so = (size_t)(i * 64) * 256 + (size_t)kw * 32;
                gload16(BsH[d] + lo, Bh + bbase + so);
                gload16(BsL[d] + lo, Bl + bbase + so);
            }
        };
        stageA(0); stageB(0, 0);
        for (int kw = 0; kw < 8; kw++) {
            int cur = kw & 1;
            asm volatile("s_waitcnt vmcnt(0)" ::: "memory");   // stage(kw) landed
            __builtin_amdgcn_s_barrier();
            bf16x8 ah[4], al[4];
            #pragma unroll
            for (int mi = 0; mi < 4; mi++) {
                ah[mi] = *(const bf16x8*)(AsH + aoff[mi]);
                al[mi] = *(const bf16x8*)(AsL + aoff[mi]);
            }
            asm volatile("s_waitcnt lgkmcnt(0)" ::: "memory");
            __builtin_amdgcn_sched_barrier(0);
            __builtin_amdgcn_s_barrier();           // all A(kw) reads retired
            if (kw < 7) { stageA(kw + 1); stageB(cur ^ 1, kw + 1); }
            #pragma unroll
            for (int nj = 0; nj < 4; nj++) {
                bf16x8 bh = *(const bf16x8*)(BsH[cur] + boff[nj]);
                bf16x8 bl = *(const bf16x8*)(BsL[cur] + boff[nj]);
                #pragma unroll
                for (int mi = 0; mi < 4; mi++) {
                    acc[mi][nj] = MFMA_BF16(ah[mi], bh, acc[mi][nj], 0, 0, 0);
                    acc[mi][nj] = MFMA_BF16(al[mi], bh, acc[mi][nj], 0, 0, 0);
                    acc[mi][nj] = MFMA_BF16(ah[mi], bl, acc[mi][nj], 0, 0, 0);
                }
            }
        }
        unsigned int* qlist = qmeta + 16;
        #pragma unroll
        for (int mi = 0; mi < 4; mi++)
            #pragma unroll
            for (int nj = 0; nj < 4; nj++)
                #pragma unroll
                for (int r = 0; r < 4; r++) {
                    int rv = M0 + wr * 64 + mi * 16 + quad * 4 + r;
                    int rp = (rv >> 3) * 24 + (rv & 7);
                    int col = n0 + wc * 64 + nj * 16 + l15;
                    float v = acc[mi][nj][r];
                    Cbf[((size_t)b * CQKV + rp) * P4096 + col] = f2bf(v);
                    qplane[((size_t)b * 256 + rv) * P4096 + col] = v;
                    if (fabsf(v) < 1e-4f) {   // sparse qfix worklist (~2.5e-4 hit rate)
                        unsigned int idx = atomicAdd(qmeta, 1u);
                        if (idx < QFIX_CAP)
                            qlist[idx] = (unsigned int)(((b * 256 + rv) << 12) | col);
                    }
                }
    } else {
        // ---- k/v rows: single term; 3-stage pipeline, vmcnt(8) ----
        char* As[3] = { smem, smem + 8192, smem + 16384 };
        char* Bs[3] = { smem + 24576, smem + 32768, smem + 40960 };
        auto stageKV = [&](int d, int kw) {
            #pragma unroll
            for (int i = 0; i < 2; i++) {
                int lo = ldsoff + i * 4096;
                size_t so = (size_t)(i * 64) * 256 + (size_t)kw * 32;
                gload16(As[d] + lo, Ah + abase + so);
                gload16(Bs[d] + lo, Bh + bbase + so);
            }
        };
        stageKV(0, 0);
        stageKV(1, 1);
        #pragma unroll
        for (int kw = 0; kw < 8; kw++) {
            int cur = kw % 3;
            if (kw < 6) {
                stageKV((kw + 2) % 3, kw + 2);
                asm volatile("s_waitcnt vmcnt(8)" ::: "memory");   // stage(kw) landed
            } else if (kw == 6) {
                asm volatile("s_waitcnt vmcnt(4)" ::: "memory");
            } else {
                asm volatile("s_waitcnt vmcnt(0)" ::: "memory");
            }
            __builtin_amdgcn_s_barrier();
            bf16x8 ah[4];
            #pragma unroll
            for (int mi = 0; mi < 4; mi++)
                ah[mi] = *(const bf16x8*)(As[cur] + aoff[mi]);
            #pragma unroll
            for (int nj = 0; nj < 4; nj++) {
                bf16x8 bh = *(const bf16x8*)(Bs[cur] + boff[nj]);
                #pragma unroll
                for (int mi = 0; mi < 4; mi++)
                    acc[mi][nj] = MFMA_BF16(ah[mi], bh, acc[mi][nj], 0, 0, 0);
            }
            __builtin_amdgcn_s_barrier();   // reads of buf[cur] done before overwrite
        }
        #pragma unroll
        for (int mi = 0; mi < 4; mi++)
            #pragma unroll
            for (int nj = 0; nj < 4; nj++)
                #pragma unroll
                for (int r = 0; r < 4; r++) {
                    int rv2 = (M0 - 256) + wr * 64 + mi * 16 + quad * 4 + r;
                    int rp = (rv2 >> 4) * 24 + 8 + (rv2 & 15);
                    int col = n0 + wc * 64 + nj * 16 + l15;
                    Cbf[((size_t)b * CQKV + rp) * P4096 + col] = f2bf(acc[mi][nj][r]);
                }
    }
}

// ---------------- qfix2: sparse fp64 recompute, one wave per worklist entry ----------------
__global__ __launch_bounds__(256) void qfix2_kernel(
    float* __restrict__ qplane, const float* __restrict__ w_qkv,
    const float* __restrict__ x, const unsigned int* __restrict__ qmeta)
{
    unsigned int n = qmeta[0];
    if (n > QFIX_CAP) n = QFIX_CAP;
    const unsigned int* list = qmeta + 16;
    const int wave = threadIdx.x >> 6, lane = threadIdx.x & 63;
    for (unsigned int e = blockIdx.x * 4 + wave; e < n; e += gridDim.x * 4) {
        unsigned int i = list[e];
        int p   = (int)(i & 4095);
        int qch = (int)((i >> 12) & 255);
        int b   = (int)(i >> 20);
        int row = (qch >> 3) * 24 + (qch & 7);
        const float* wr = w_qkv + (size_t)row * 256;
        const float* xr = x + (size_t)b * 256 * P4096 + p;
        double s = 0.0;
        #pragma unroll
        for (int j = 0; j < 4; j++) {
            int c = lane * 4 + j;
            s += (double)wr[c] * (double)xr[(size_t)c * P4096];
        }
        #pragma unroll
        for (int off = 32; off > 0; off >>= 1) s += __shfl_xor(s, off, 64);
        if (lane == 0)
            qplane[((size_t)(b * 256 + qch)) * P4096 + p] = (float)s;
    }
}

// ---------------- dw 3x3 + grouped pw (bf16; feeds only heads 32-63) ----------------
__global__ __launch_bounds__(512, 8) void dwpw_kernel(
    const ushort* __restrict__ qkv, const float* __restrict__ wdw,
    const float* __restrict__ wpw, ushort* __restrict__ agg)
{
    const int rt = blockIdx.x;    // 0..3 (16 output rows each)
    const int g  = blockIdx.y;    // 0..95
    const int b  = blockIdx.z;
    const int t  = threadIdx.x;   // 0..511
    const int r0 = rt * 16;
    const int cg = g * 8;

    __shared__ __align__(16) ushort tile[8][18][80];   // 23040 B

    const ushort* src = qkv + ((size_t)(b * CQKV + cg)) * P4096;

    if (t < 288) {
        int ch = t / 36;
        int rr = (t % 36) >> 1;
        int side = t & 1;
        *(uint4*)&tile[ch][rr][side * 72] = make_uint4(0, 0, 0, 0);
    }
    #pragma unroll
    for (int i = 0; i < 3; i++) {
        int id = t + i * 512;
        if (id < 1152) {
            int ch  = id / 144;
            int rem = id - ch * 144;
            int rr  = rem >> 3;
            int oct = (rem & 7) * 8;
            int grow = r0 - 1 + rr;
            uint4 v = make_uint4(0, 0, 0, 0);
            if (grow >= 0 && grow < 64)
                v = *(const uint4*)(src + (size_t)ch * P4096 + (size_t)grow * 64 + oct);
            *(uint4*)&tile[ch][rr][8 + oct] = v;
        }
    }
    __syncthreads();

    const int kc  = t & 31;        // col pair: cols 2kc, 2kc+1
    const int row = t >> 5;        // 0..15
    const float* wdwg = wdw + (size_t)cg * 9;   // block-uniform -> s_load
    const float* wpwg = wpw + (size_t)cg * 8;

    float acc0[8], acc1[8];
    #pragma unroll
    for (int oi = 0; oi < 8; oi++) { acc0[oi] = 0.0f; acc1[oi] = 0.0f; }

    #pragma unroll
    for (int c = 0; c < 8; c++) {
        float dv0 = 0.0f, dv1 = 0.0f;
        #pragma unroll
        for (int dy = 0; dy < 3; dy++) {
            const ushort* rp = &tile[c][row + dy][2 * kc + 4];
            unsigned int u1 = *(const unsigned int*)(rp + 2);
            unsigned int u2 = *(const unsigned int*)(rp + 4);
            unsigned int u3 = *(const unsigned int*)(rp + 6);
            float xm1 = __uint_as_float(u1 & 0xffff0000u);
            float x0  = __uint_as_float(u2 << 16);
            float x1  = __uint_as_float(u2 & 0xffff0000u);
            float x2  = __uint_as_float(u3 << 16);
            float w0 = wdwg[c * 9 + dy * 3 + 0];
            float w1 = wdwg[c * 9 + dy * 3 + 1];
            float w2 = wdwg[c * 9 + dy * 3 + 2];
            dv0 = fmaf(w0, xm1, dv0); dv0 = fmaf(w1, x0, dv0); dv0 = fmaf(w2, x1, dv0);
            dv1 = fmaf(w0, x0,  dv1); dv1 = fmaf(w1, x1, dv1); dv1 = fmaf(w2, x2, dv1);
        }
        #pragma unroll
        for (int oi = 0; oi < 8; oi++) {
            float w = wpwg[oi * 8 + c];
            acc0[oi] = fmaf(w, dv0, acc0[oi]);
            acc1[oi] = fmaf(w, dv1, acc1[oi]);
        }
    }

    size_t obase = ((size_t)(b * CQKV + cg)) * P4096 + (size_t)(r0 + row) * 64 + 2 * kc;
    #pragma unroll
    for (int oi = 0; oi < 8; oi++) {
        unsigned int u = (unsigned int)f2bf(acc0[oi]) |
                         ((unsigned int)f2bf(acc1[oi]) << 16);
        *(unsigned int*)&agg[obase + (size_t)oi * P4096] = u;
    }
}

// ---------------- kv[b,h,d,e] = sum_p relu(k_d)*v_e  (v_8 = 1) ----------------
// Writes into kvslot() region (qkv_bf b0 q-planes, dead after dwpw).
__global__ __launch_bounds__(256) void kv_kernel(
    const ushort* __restrict__ qkv, const ushort* __restrict__ agg,
    ushort* __restrict__ kvdst)
{
    const int h = blockIdx.x, b = blockIdx.y, t = threadIdx.x;
    const ushort* src = (h < 32)
        ? qkv + ((size_t)(b * CQKV + h * 24)) * P4096
        : agg + ((size_t)(b * CQKV + (h - 32) * 24)) * P4096;

    float acc[72];
    #pragma unroll
    for (int i = 0; i < 72; i++) acc[i] = 0.0f;

    for (int pi = 0; pi < 16; pi++) {
        int p = t + pi * 256;
        float kvv[8], vv[8];
        #pragma unroll
        for (int d = 0; d < 8; d++) {
            float xk = bf2f(src[(size_t)(8 + d) * P4096 + p]);
            kvv[d] = xk > 0.0f ? xk : 0.0f;
        }
        #pragma unroll
        for (int e = 0; e < 8; e++) vv[e] = bf2f(src[(size_t)(16 + e) * P4096 + p]);
        #pragma unroll
        for (int d = 0; d < 8; d++) {
            #pragma unroll
            for (int e = 0; e < 8; e++) acc[d * 9 + e] += kvv[d] * vv[e];
            acc[d * 9 + 8] += kvv[d];
        }
    }

    #pragma unroll
    for (int i = 0; i < 72; i++) {
        float v = acc[i];
        #pragma unroll
        for (int off = 32; off > 0; off >>= 1) v += __shfl_xor(v, off, 64);
        acc[i] = v;
    }
    __shared__ float part[4][72];
    int wave = t >> 6, lane = t & 63;
    if (lane == 0) {
        #pragma unroll
        for (int i = 0; i < 72; i++) part[wave][i] = acc[i];
    }
    __syncthreads();
    if (t < 72)
        *kvslot(kvdst, (unsigned int)(b * 64 + h) * 72u + t) =
            part[0][t] + part[1][t] + part[2][t] + part[3][t];
}

// ---------------- GEMM3 v3: y = W_proj @ attn_out(q,kv), attn fused ----------------
// B computed on the fly: out[kk][px] = f2bf(num_e/(den+1e-15)) from q (qplane
// fp32 heads<32 / agg bf16 q-slots heads>=32) and kv[b] preloaded to LDS.
// Bit-identical to the old attn_out->agg->proj path. A from Awp (in qkv dead
// k/v planes). 128x128 tile, dbuf, issue-early/write-late.
__global__ __launch_bounds__(256, 2) void gemm_proj(
    const ushort* __restrict__ qkv,    // Awp chunks + kvbuf (kvslot)
    const ushort* __restrict__ agg,    // hi-head q in q-slots
    const float* __restrict__ qplane,  // lo-head q fp32
    float* __restrict__ Y,
    const float* __restrict__ bn_g, const float* __restrict__ bn_b,
    const float* __restrict__ bn_m, const float* __restrict__ bn_v)
{
    const int hw = blockIdx.x;                 // 0..1023
    const int lg = (hw & 7) * 128 + (hw >> 3);
    const int mt = lg & 1;
    const int rem = lg >> 1;                   // 0..511
    const int n0 = (rem & 31) * 128;
    const int b  = rem >> 5;
    const int t  = threadIdx.x;
    const int wave = t >> 6, lane = t & 63, quad = lane >> 4, l15 = lane & 15;
    const int wr = wave >> 1, wc = wave & 1;
    const int M0 = mt * 128;

    __shared__ __align__(16) ushort As[2][4096];   // [128][32]
    __shared__ __align__(16) ushort Bs[2][5120];   // [128][40]
    __shared__ float kvs[64][72];                  // 18432 B; total 55296 B

    int aoff[4], boff[4];
    #pragma unroll
    for (int i = 0; i < 4; i++) {
        int ra = wr * 64 + i * 16 + l15;
        aoff[i] = ra * 64 + ((quad ^ ((ra >> 1) & 3)) << 4);   // bytes
        int rb = wc * 64 + i * 16 + l15;
        boff[i] = rb * 80 + quad * 16;                          // bytes, pad-40 rows
    }

    // A source: Awp chunk mt (row-local 0..127, 512 ushorts/row)
    const ushort* AwpC = qkv + (mt ? (size_t)32 * 4096 : (size_t)8 * 4096);
    const int arow0 = t >> 2, achk = (t & 3) * 8;
    const size_t abase  = (size_t)arow0 * 512 + achk;
    const size_t abase1 = (size_t)(64 + arow0) * 512 + achk;
    const int ldsoffA = wave * 1024;   // bytes; +4096 for i=1

    const int bn_ = t & 127, half = t >> 7;
    const int px = n0 + bn_;

    // preload kv[b] (64 heads x 72) into LDS
    for (int i = t; i < 4608; i += 256)
        kvs[i / 72][i % 72] = *kvslot(qkv, (unsigned int)b * 4608u + i);

    f32x4 acc[4][4];
    #pragma unroll
    for (int mi = 0; mi < 4; mi++)
        #pragma unroll
        for (int nj = 0; nj < 4; nj++)
            #pragma unroll
            for (int r = 0; r < 4; r++) acc[mi][nj][r] = 0.0f;

    auto stageA = [&](int d, int kw) {
        gload16((char*)As[d] + ldsoffA,        AwpC + abase  + (size_t)kw * 32);
        gload16((char*)As[d] + ldsoffA + 4096, AwpC + abase1 + (size_t)kw * 32);
    };
    float qreg[2][8];
    auto loadQ = [&](int kw) {
        int hd0 = kw * 4 + half * 2;           // first of 2 heads this half
        #pragma unroll
        for (int hh = 0; hh < 2; hh++) {
            int hd = hd0 + hh;
            if (hd < 32) {
                #pragma unroll
                for (int d = 0; d < 8; d++)
                    qreg[hh][d] = qplane[((size_t)(b * 256 + hd * 8 + d)) * P4096 + px];
            } else {
                #pragma unroll
                for (int d = 0; d < 8; d++)
                    qreg[hh][d] = bf2f(agg[((size_t)(b * CQKV + (hd - 32) * 24 + d)) * P4096 + px]);
            }
        }
    };
    ushort bu[16];
    auto computeB = [&](int kw) {
        int hd0 = kw * 4 + half * 2;
        #pragma unroll
        for (int hh = 0; hh < 2; hh++) {
            int hd = hd0 + hh;
            float num[8]; float den = 0.0f;
            #pragma unroll
            for (int e = 0; e < 8; e++) num[e] = 0.0f;
            #pragma unroll
            for (int d = 0; d < 8; d++) {
                float q = qreg[hh][d];
                q = q > 0.0f ? q : 0.0f;
                #pragma unroll
                for (int e = 0; e < 8; e++) num[e] += q * kvs[hd][d * 9 + e];
                den += q * kvs[hd][d * 9 + 8];
            }
            float rd = 1.0f / (den + 1e-15f);
            #pragma unroll
            for (int e = 0; e < 8; e++) bu[hh * 8 + e] = f2bf(num[e] * rd);
        }
    };
    auto writeB = [&](int d) {
        union { ushort us[8]; uint4 q; } P0, P1;
        #pragma unroll
        for (int j = 0; j < 8; j++) { P0.us[j] = bu[j]; P1.us[j] = bu[8 + j]; }
        ushort* dst = &Bs[d][bn_ * 40 + half * 16];
        *(uint4*)dst = P0.q;
        *(uint4*)(dst + 8) = P1.q;
    };

    // prologue: kvs preload + stage(0) + q(0); full drain; build B(0)
    stageA(0, 0);
    loadQ(0);
    __syncthreads();                 // drains vmcnt+lgkm (kvs, A, q) + barrier
    computeB(0);
    writeB(0);
    asm volatile("s_waitcnt lgkmcnt(0)" ::: "memory");
    __builtin_amdgcn_s_barrier();

    for (int kw = 0; kw < 16; kw++) {
        int cur = kw & 1;
        if (kw < 15) {
            stageA(cur ^ 1, kw + 1);
            loadQ(kw + 1);
        }
        bf16x8 af[4];
        #pragma unroll
        for (int mi = 0; mi < 4; mi++)
            af[mi] = *(const bf16x8*)((const char*)As[cur] + aoff[mi]);
        #pragma unroll
        for (int nj = 0; nj < 4; nj++) {
            bf16x8 bf = *(const bf16x8*)((const char*)Bs[cur] + boff[nj]);
            #pragma unroll
            for (int mi = 0; mi < 4; mi++)
                acc[mi][nj] = MFMA_BF16(af[mi], bf, acc[mi][nj], 0, 0, 0);
        }
        __builtin_amdgcn_s_barrier();       // all reads of buf[cur] complete
        if (kw < 15) {
            asm volatile("s_waitcnt vmcnt(0)" ::: "memory");  // A(next) in LDS, q(next) in regs
            computeB(kw + 1);
            writeB(cur ^ 1);
            asm volatile("s_waitcnt lgkmcnt(0)" ::: "memory");
        }
        __builtin_amdgcn_s_barrier();
    }

    #pragma unroll
    for (int mi = 0; mi < 4; mi++)
        #pragma unroll
        for (int nj = 0; nj < 4; nj++)
            #pragma unroll
            for (int r = 0; r < 4; r++) {
                int row = M0 + wr * 64 + mi * 16 + quad * 4 + r;
                int col = n0 + wc * 64 + nj * 16 + l15;
                float inv = bn_g[row] / sqrtf(bn_v[row] + 1e-5f);
                float v = acc[mi][nj][r] * inv + (bn_b[row] - bn_m[row] * inv);
                Y[((size_t)b * 256 + row) * P4096 + col] = v;
            }
}

// ---------------- launch ----------------
extern "C" void kernel_launch(void* const* d_in, const int* in_sizes, int n_in,
                              void* d_out, int out_size, void* d_ws, size_t ws_size,
                              hipStream_t stream) {
    const float* x      = (const float*)d_in[0];
    const float* w_qkv  = (const float*)d_in[1];
    const float* w_dw   = (const float*)d_in[2];
    const float* w_pw   = (const float*)d_in[3];
    const float* w_proj = (const float*)d_in[4];
    const float* bn_g   = (const float*)d_in[5];
    const float* bn_b   = (const float*)d_in[6];
    const float* bn_m   = (const float*)d_in[7];
    const float* bn_v   = (const float*)d_in[8];
    float* y = (float*)d_out;

    char* ws = (char*)d_ws;
    ushort* qkv_bf = (ushort*)(ws);                  // 96 MiB: bf16 768ch (+ kvbuf/Awp dead-space)
    float*  qplane = (float*) (ws + 100663296);      // 64 MiB: fp32 q (heads 0-31)
    ushort* agg_bf = (ushort*)(ws + 167772160);      // 96 MiB: agg
    // aliases inside agg region, dead once dwpw runs:
    ushort* XTh = (ushort*)(ws + 167772160);                       // 32 MiB
    ushort* XTl = (ushort*)(ws + 167772160 + 33554432);            // 32 MiB
    ushort* Awh = (ushort*)(ws + 167772160 + 67108864);            // 384 KiB
    ushort* Awl = (ushort*)(ws + 167772160 + 67108864 + 393216);   // 384 KiB
    unsigned int* qmeta = (unsigned int*)((char*)d_out + 524288);  // cnt + 8MB worklist

    conv_w<<<dim3(768), 128, 0, stream>>>(w_qkv, Awh, Awl, qmeta);
    conv_x<<<dim3(64, 4, NB), 256, 0, stream>>>(x, XTh, XTl);

    gemm_fused<<<dim3(3072), 256, 0, stream>>>(
        Awh, Awl, XTh, XTl, qkv_bf, qplane, qmeta);

    qfix2_kernel<<<dim3(1024), 256, 0, stream>>>(qplane, w_qkv, x, qmeta);

    dwpw_kernel<<<dim3(4, 96, NB), 512, 0, stream>>>(qkv_bf, w_dw, w_pw, agg_bf);

    kv_kernel<<<dim3(64, NB), 256, 0, stream>>>(qkv_bf, agg_bf, qkv_bf);

    conv_wp<<<dim3(256), 256, 0, stream>>>(w_proj, qkv_bf);  // into qkv dead k/v planes

    gemm_proj<<<dim3(1024), 256, 0, stream>>>(
        qkv_bf, agg_bf, qplane, y, bn_g, bn_b, bn_m, bn_v);
}

// Round 13
// 388.304 us; speedup vs baseline: 1.0726x; 1.0726x over previous
//
#include <hip/hip_runtime.h>
#include <hip/hip_bf16.h>

// LiteMSA pipeline, MI355X gfx950.
// B=16, Cin=256, Cqkv=768, H=W=64 (P=4096), heads=64 (24 ch: q8,k8,v8),
// out 512 ch -> proj 256 ch + BN. Output y fp32.
//
// v12 = v10 (best, 384.8us) + launch merges for concurrency:
//   conv_wx  = conv_x + conv_w (+qmeta zero)   [extra blocks]
//   dwpw_qfix = dwpw + qfix2                   [extra blocks; independent
//              work runs concurrently instead of serially]
// R12's attn-into-proj fusion REVERTED (lockstep barriers serialized the
// attn VALU with MFMA: proj 40->116us). Numerics bitwise unchanged.
//
// ws (256 MiB):
//   qkv_bf [0,96M)    bf16 768ch
//   qplane [96M,160M) fp32 256ch (q of heads 0-31); REUSED after attn_out
//                     for Awp (w_proj bf16 256x512, 256KB)
//   agg_bf [160M,256M) bf16 768ch; ALIASED before dwpw by XTh/XTl/Awh/Awl
// d_out: kvbuf 288K scratch at head; qmeta (cnt + worklist) at +512K.

#define NB 16
#define CQKV 768
#define P4096 4096
#define QFIX_CAP (1u << 21)

typedef __bf16 bf16x8 __attribute__((ext_vector_type(8)));
typedef float f32x4 __attribute__((ext_vector_type(4)));

#define MFMA_BF16 __builtin_amdgcn_mfma_f32_16x16x32_bf16

__device__ __forceinline__ ushort f2bf(float f) {
    union { float f; unsigned int u; } x; x.f = f;
    unsigned int u = x.u;
    unsigned int r = (u + 0x7FFFu + ((u >> 16) & 1u)) >> 16;
    return (ushort)r;
}
__device__ __forceinline__ float bf2f(ushort u) {
    union { unsigned int u; float f; } x; x.u = ((unsigned int)u) << 16;
    return x.f;
}
__device__ __forceinline__ unsigned int pk2bf(float x, float y) {
    __hip_bfloat162 h = __float22bfloat162_rn(make_float2(x, y));  // v_cvt_pk_bf16_f32 (RNE)
    union { __hip_bfloat162 b; unsigned int u; } c; c.b = h; return c.u;
}

__device__ __forceinline__ void gload16(void* lds, const void* g) {
    __builtin_amdgcn_global_load_lds(
        (const __attribute__((address_space(1))) void*)g,
        (__attribute__((address_space(3))) void*)lds, 16, 0, 0);
}

// ---------------- conv_wx: conv_x (bid<4096) + conv_w (bid>=4096, +zero qmeta) ----------------
// conv_x: x [b][256][4096] f32 -> XT hi/lo [b][4096][256] bf16, swizzled.
// conv_w: w_qkv -> virt-row-ordered swizzled bf16 hi/lo.
//   virt rows: 0..255 q (phys=(v>>3)*24+v&7), 256..767 kv (phys=(v2>>4)*24+8+v2&15).
__global__ __launch_bounds__(256) void conv_wx(
    const float* __restrict__ X, const float* __restrict__ W,
    ushort* __restrict__ XTh, ushort* __restrict__ XTl,
    ushort* __restrict__ Ah, ushort* __restrict__ Al,
    unsigned int* __restrict__ qmeta)
{
    const int bid = blockIdx.x;
    const int t = threadIdx.x;
    __shared__ float tile[64][65];

    if (bid < 4096) {
        const int pt = bid & 63, ct = (bid >> 6) & 3, b = bid >> 8;
        const int p0 = pt * 64, c0 = ct * 64;
        {
            int cr = t >> 2, pc = (t & 3) * 16;
            const float* xr = X + ((size_t)b * 256 + c0 + cr) * P4096 + p0 + pc;
            float4 v0 = *(const float4*)xr;
            float4 v1 = *(const float4*)(xr + 4);
            float4 v2 = *(const float4*)(xr + 8);
            float4 v3 = *(const float4*)(xr + 12);
            float* d = &tile[cr][pc];
            d[0]=v0.x; d[1]=v0.y; d[2]=v0.z; d[3]=v0.w;
            d[4]=v1.x; d[5]=v1.y; d[6]=v1.z; d[7]=v1.w;
            d[8]=v2.x; d[9]=v2.y; d[10]=v2.z; d[11]=v2.w;
            d[12]=v3.x; d[13]=v3.y; d[14]=v3.z; d[15]=v3.w;
        }
        __syncthreads();
        #pragma unroll
        for (int pass = 0; pass < 2; pass++) {
            int tp = t >> 2;
            int cc = (t & 3) + pass * 4;      // 0..7 chunk of 8 c
            int p  = p0 + tp;
            float v[8];
            #pragma unroll
            for (int j = 0; j < 8; j++) v[j] = tile[cc * 8 + j][tp];
            union { unsigned int u[4]; uint4 q; } H, L;
            #pragma unroll
            for (int i = 0; i < 4; i++) {
                unsigned int h = pk2bf(v[2 * i], v[2 * i + 1]);
                H.u[i] = h;
                float f0 = __uint_as_float(h << 16);
                float f1 = __uint_as_float(h & 0xffff0000u);
                L.u[i] = pk2bf(v[2 * i] - f0, v[2 * i + 1] - f1);
            }
            int c = c0 + cc * 8;
            int sl = ((c >> 3) & 3) ^ ((p >> 1) & 3);
            size_t idx = ((size_t)b * P4096 + p) * 256 + (c & ~31) + sl * 8;
            *(uint4*)&XTh[idx] = H.q;
            *(uint4*)&XTl[idx] = L.q;
        }
    } else {
        const int rv = bid - 4096;     // 0..767
        if (rv == 0 && t == 0) qmeta[0] = 0;
        if (t < 128) {
            int phys;
            if (rv < 256) phys = (rv >> 3) * 24 + (rv & 7);
            else { int r2 = rv - 256; phys = (r2 >> 4) * 24 + 8 + (r2 & 15); }
            int c = t * 2;
            float w0 = W[(size_t)phys * 256 + c];
            float w1 = W[(size_t)phys * 256 + c + 1];
            unsigned int h = pk2bf(w0, w1);
            float f0 = __uint_as_float(h << 16);
            float f1 = __uint_as_float(h & 0xffff0000u);
            unsigned int l = pk2bf(w0 - f0, w1 - f1);
            int sl = ((c >> 3) & 3) ^ ((rv >> 1) & 3);
            int idx = (c & ~31) + sl * 8 + (c & 7);
            *(unsigned int*)&Ah[(size_t)rv * 256 + idx] = h;
            *(unsigned int*)&Al[(size_t)rv * 256 + idx] = l;
        }
    }
}

// ---------------- conv_wp: w_proj 256x512 -> swizzled bf16 (into dead qplane region) ----------------
__global__ __launch_bounds__(256) void conv_wp(
    const float* __restrict__ W, ushort* __restrict__ Awp)
{
    const int m = blockIdx.x;      // 0..255
    const int t = threadIdx.x;     // 0..255 -> c pair
    int c = t * 2;
    float w0 = W[(size_t)m * 512 + c];
    float w1 = W[(size_t)m * 512 + c + 1];
    unsigned int h = pk2bf(w0, w1);
    int sl = ((c >> 3) & 3) ^ ((m >> 1) & 3);
    int idx = (c & ~31) + sl * 8 + (c & 7);
    *(unsigned int*)&Awp[(size_t)m * 512 + idx] = h;
}

// ---------------- gemm_fused: all 768 virt rows; q tiles 3-term, kv tiles 1-term ----------------
// 128x128 tile, BK=32, 4 waves (2x2), 48KB LDS -> 3 blocks/CU.
// q branch: A (L2-hot) single-buffered, B double-buffered.
// kv branch: 3-stage pipeline, counted vmcnt(8).
// Grid 3072, XCD swizzle. q epilogue emits sparse qfix worklist.
__global__ __launch_bounds__(256, 3) void gemm_fused(
    const ushort* __restrict__ Ah, const ushort* __restrict__ Al,
    const ushort* __restrict__ Bh, const ushort* __restrict__ Bl,
    ushort* __restrict__ Cbf, float* __restrict__ qplane,
    unsigned int* __restrict__ qmeta)
{
    const int hw = blockIdx.x;                 // 0..3071
    const int lg = (hw & 7) * 384 + (hw >> 3); // XCD-contiguous logical id
    const int mt = lg % 6;
    const int rem = lg / 6;                    // 0..511
    const int n0 = (rem & 31) * 128;
    const int b  = rem >> 5;
    const int t  = threadIdx.x;
    const int wave = t >> 6, lane = t & 63, quad = lane >> 4, l15 = lane & 15;
    const int wr = wave >> 1, wc = wave & 1;
    const int M0 = mt * 128;

    __shared__ __align__(16) char smem[49152];   // 48 KB

    int aoff[4], boff[4];
    #pragma unroll
    for (int i = 0; i < 4; i++) {
        int ra = wr * 64 + i * 16 + l15;
        aoff[i] = ra * 64 + ((quad ^ ((ra >> 1) & 3)) << 4);
        int rb = wc * 64 + i * 16 + l15;
        boff[i] = rb * 64 + ((quad ^ ((rb >> 1) & 3)) << 4);
    }

    const int srow = t >> 2;               // 0..63
    const int schunk = (t & 3) * 8;        // ushort offset in 32-ushort window
    const size_t abase = (size_t)(M0 + srow) * 256 + schunk;
    const size_t bbase = ((size_t)b * P4096 + n0 + srow) * 256 + schunk;
    const int ldsoff = wave * 1024;        // bytes; +i*4096

    f32x4 acc[4][4];
    #pragma unroll
    for (int mi = 0; mi < 4; mi++)
        #pragma unroll
        for (int nj = 0; nj < 4; nj++)
            #pragma unroll
            for (int r = 0; r < 4; r++) acc[mi][nj][r] = 0.0f;

    if (mt < 2) {
        // ---- q rows: 3-term split; single-A (16K) + double-B (32K) ----
        char* AsH = smem;                  // 8K
        char* AsL = smem + 8192;           // 8K
        char* BsH[2] = { smem + 16384, smem + 24576 };
        char* BsL[2] = { smem + 32768, smem + 40960 };

        auto stageA = [&](int kw) {
            #pragma unroll
            for (int i = 0; i < 2; i++) {
                int lo = ldsoff + i * 4096;
                size_t so = (size_t)(i * 64) * 256 + (size_t)kw * 32;
                gload16(AsH + lo, Ah + abase + so);
                gload16(AsL + lo, Al + abase + so);
            }
        };
        auto stageB = [&](int d, int kw) {
            #pragma unroll
            for (int i = 0; i < 2; i++) {
                int lo = ldsoff + i * 4096;
                size_t so = (size_t)(i * 64) * 256 + (size_t)kw * 32;
                gload16(BsH[d] + lo, Bh + bbase + so);
                gload16(BsL[d] + lo, Bl + bbase + so);
            }
        };
        stageA(0); stageB(0, 0);
        for (int kw = 0; kw < 8; kw++) {
            int cur = kw & 1;
            asm volatile("s_waitcnt vmcnt(0)" ::: "memory");   // stage(kw) landed
            __builtin_amdgcn_s_barrier();
            bf16x8 ah[4], al[4];
            #pragma unroll
            for (int mi = 0; mi < 4; mi++) {
                ah[mi] = *(const bf16x8*)(AsH + aoff[mi]);
                al[mi] = *(const bf16x8*)(AsL + aoff[mi]);
            }
            asm volatile("s_waitcnt lgkmcnt(0)" ::: "memory");
            __builtin_amdgcn_sched_barrier(0);
            __builtin_amdgcn_s_barrier();           // all A(kw) reads retired
            if (kw < 7) { stageA(kw + 1); stageB(cur ^ 1, kw + 1); }
            #pragma unroll
            for (int nj = 0; nj < 4; nj++) {
                bf16x8 bh = *(const bf16x8*)(BsH[cur] + boff[nj]);
                bf16x8 bl = *(const bf16x8*)(BsL[cur] + boff[nj]);
                #pragma unroll
                for (int mi = 0; mi < 4; mi++) {
                    acc[mi][nj] = MFMA_BF16(ah[mi], bh, acc[mi][nj], 0, 0, 0);
                    acc[mi][nj] = MFMA_BF16(al[mi], bh, acc[mi][nj], 0, 0, 0);
                    acc[mi][nj] = MFMA_BF16(ah[mi], bl, acc[mi][nj], 0, 0, 0);
                }
            }
        }
        unsigned int* qlist = qmeta + 16;
        #pragma unroll
        for (int mi = 0; mi < 4; mi++)
            #pragma unroll
            for (int nj = 0; nj < 4; nj++)
                #pragma unroll
                for (int r = 0; r < 4; r++) {
                    int rv = M0 + wr * 64 + mi * 16 + quad * 4 + r;
                    int rp = (rv >> 3) * 24 + (rv & 7);
                    int col = n0 + wc * 64 + nj * 16 + l15;
                    float v = acc[mi][nj][r];
                    Cbf[((size_t)b * CQKV + rp) * P4096 + col] = f2bf(v);
                    qplane[((size_t)b * 256 + rv) * P4096 + col] = v;
                    if (fabsf(v) < 1e-4f) {   // sparse qfix worklist (~2.5e-4 hit rate)
                        unsigned int idx = atomicAdd(qmeta, 1u);
                        if (idx < QFIX_CAP)
                            qlist[idx] = (unsigned int)(((b * 256 + rv) << 12) | col);
                    }
                }
    } else {
        // ---- k/v rows: single term; 3-stage pipeline, vmcnt(8) ----
        char* As[3] = { smem, smem + 8192, smem + 16384 };
        char* Bs[3] = { smem + 24576, smem + 32768, smem + 40960 };
        auto stageKV = [&](int d, int kw) {
            #pragma unroll
            for (int i = 0; i < 2; i++) {
                int lo = ldsoff + i * 4096;
                size_t so = (size_t)(i * 64) * 256 + (size_t)kw * 32;
                gload16(As[d] + lo, Ah + abase + so);
                gload16(Bs[d] + lo, Bh + bbase + so);
            }
        };
        stageKV(0, 0);
        stageKV(1, 1);
        #pragma unroll
        for (int kw = 0; kw < 8; kw++) {
            int cur = kw % 3;
            if (kw < 6) {
                stageKV((kw + 2) % 3, kw + 2);
                asm volatile("s_waitcnt vmcnt(8)" ::: "memory");   // stage(kw) landed
            } else if (kw == 6) {
                asm volatile("s_waitcnt vmcnt(4)" ::: "memory");
            } else {
                asm volatile("s_waitcnt vmcnt(0)" ::: "memory");
            }
            __builtin_amdgcn_s_barrier();
            bf16x8 ah[4];
            #pragma unroll
            for (int mi = 0; mi < 4; mi++)
                ah[mi] = *(const bf16x8*)(As[cur] + aoff[mi]);
            #pragma unroll
            for (int nj = 0; nj < 4; nj++) {
                bf16x8 bh = *(const bf16x8*)(Bs[cur] + boff[nj]);
                #pragma unroll
                for (int mi = 0; mi < 4; mi++)
                    acc[mi][nj] = MFMA_BF16(ah[mi], bh, acc[mi][nj], 0, 0, 0);
            }
            __builtin_amdgcn_s_barrier();   // reads of buf[cur] done before overwrite
        }
        #pragma unroll
        for (int mi = 0; mi < 4; mi++)
            #pragma unroll
            for (int nj = 0; nj < 4; nj++)
                #pragma unroll
                for (int r = 0; r < 4; r++) {
                    int rv2 = (M0 - 256) + wr * 64 + mi * 16 + quad * 4 + r;
                    int rp = (rv2 >> 4) * 24 + 8 + (rv2 & 15);
                    int col = n0 + wc * 64 + nj * 16 + l15;
                    Cbf[((size_t)b * CQKV + rp) * P4096 + col] = f2bf(acc[mi][nj][r]);
                }
    }
}

// ---------------- dwpw_qfix: dwpw (bid<6144) + sparse qfix2 (bid>=6144) ----------------
// dwpw: dw 3x3 + grouped pw (bf16; feeds only heads 32-63).
// qfix2: fp64 recompute of worklist entries (one wave per entry).
// Independent work merged into one launch -> runs concurrently.
__global__ __launch_bounds__(512, 8) void dwpw_qfix(
    const ushort* __restrict__ qkv, const float* __restrict__ wdw,
    const float* __restrict__ wpw, ushort* __restrict__ agg,
    float* __restrict__ qplane, const float* __restrict__ w_qkv,
    const float* __restrict__ x, const unsigned int* __restrict__ qmeta)
{
    const int bid = blockIdx.x;
    const int t = threadIdx.x;     // 0..511
    __shared__ __align__(16) ushort tile[8][18][80];   // 23040 B

    if (bid < 6144) {
        const int rt = bid & 3;            // 0..3 (16 output rows each)
        const int rest = bid >> 2;
        const int g = rest % 96;           // 0..95
        const int b = rest / 96;           // 0..15
        const int r0 = rt * 16;
        const int cg = g * 8;

        const ushort* src = qkv + ((size_t)(b * CQKV + cg)) * P4096;

        if (t < 288) {
            int ch = t / 36;
            int rr = (t % 36) >> 1;
            int side = t & 1;
            *(uint4*)&tile[ch][rr][side * 72] = make_uint4(0, 0, 0, 0);
        }
        #pragma unroll
        for (int i = 0; i < 3; i++) {
            int id = t + i * 512;
            if (id < 1152) {
                int ch  = id / 144;
                int rem = id - ch * 144;
                int rr  = rem >> 3;
                int oct = (rem & 7) * 8;
                int grow = r0 - 1 + rr;
                uint4 v = make_uint4(0, 0, 0, 0);
                if (grow >= 0 && grow < 64)
                    v = *(const uint4*)(src + (size_t)ch * P4096 + (size_t)grow * 64 + oct);
                *(uint4*)&tile[ch][rr][8 + oct] = v;
            }
        }
        __syncthreads();

        const int kc  = t & 31;        // col pair: cols 2kc, 2kc+1
        const int row = t >> 5;        // 0..15
        const float* wdwg = wdw + (size_t)cg * 9;   // block-uniform -> s_load
        const float* wpwg = wpw + (size_t)cg * 8;

        float acc0[8], acc1[8];
        #pragma unroll
        for (int oi = 0; oi < 8; oi++) { acc0[oi] = 0.0f; acc1[oi] = 0.0f; }

        #pragma unroll
        for (int c = 0; c < 8; c++) {
            float dv0 = 0.0f, dv1 = 0.0f;
            #pragma unroll
            for (int dy = 0; dy < 3; dy++) {
                const ushort* rp = &tile[c][row + dy][2 * kc + 4];
                unsigned int u1 = *(const unsigned int*)(rp + 2);
                unsigned int u2 = *(const unsigned int*)(rp + 4);
                unsigned int u3 = *(const unsigned int*)(rp + 6);
                float xm1 = __uint_as_float(u1 & 0xffff0000u);
                float x0  = __uint_as_float(u2 << 16);
                float x1  = __uint_as_float(u2 & 0xffff0000u);
                float x2  = __uint_as_float(u3 << 16);
                float w0 = wdwg[c * 9 + dy * 3 + 0];
                float w1 = wdwg[c * 9 + dy * 3 + 1];
                float w2 = wdwg[c * 9 + dy * 3 + 2];
                dv0 = fmaf(w0, xm1, dv0); dv0 = fmaf(w1, x0, dv0); dv0 = fmaf(w2, x1, dv0);
                dv1 = fmaf(w0, x0,  dv1); dv1 = fmaf(w1, x1, dv1); dv1 = fmaf(w2, x2, dv1);
            }
            #pragma unroll
            for (int oi = 0; oi < 8; oi++) {
                float w = wpwg[oi * 8 + c];
                acc0[oi] = fmaf(w, dv0, acc0[oi]);
                acc1[oi] = fmaf(w, dv1, acc1[oi]);
            }
        }

        size_t obase = ((size_t)(b * CQKV + cg)) * P4096 + (size_t)(r0 + row) * 64 + 2 * kc;
        #pragma unroll
        for (int oi = 0; oi < 8; oi++) {
            unsigned int u = (unsigned int)f2bf(acc0[oi]) |
                             ((unsigned int)f2bf(acc1[oi]) << 16);
            *(unsigned int*)&agg[obase + (size_t)oi * P4096] = u;
        }
    } else {
        // ---- qfix2: sparse fp64 recompute ----
        unsigned int n = qmeta[0];
        if (n > QFIX_CAP) n = QFIX_CAP;
        const unsigned int* list = qmeta + 16;
        const int wave = t >> 6, lane = t & 63;
        for (unsigned int e = (unsigned int)(bid - 6144) * 8 + wave; e < n; e += 256 * 8) {
            unsigned int i = list[e];
            int p   = (int)(i & 4095);
            int qch = (int)((i >> 12) & 255);
            int b   = (int)(i >> 20);
            int row = (qch >> 3) * 24 + (qch & 7);
            const float* wr = w_qkv + (size_t)row * 256;
            const float* xr = x + (size_t)b * 256 * P4096 + p;
            double s = 0.0;
            #pragma unroll
            for (int j = 0; j < 4; j++) {
                int c = lane * 4 + j;
                s += (double)wr[c] * (double)xr[(size_t)c * P4096];
            }
            #pragma unroll
            for (int off = 32; off > 0; off >>= 1) s += __shfl_xor(s, off, 64);
            if (lane == 0)
                qplane[((size_t)(b * 256 + qch)) * P4096 + p] = (float)s;
        }
    }
}

// ---------------- kv[b,h,d,e] = sum_p relu(k_d)*v_e  (v_8 = 1) ----------------
__global__ __launch_bounds__(256) void kv_kernel(
    const ushort* __restrict__ qkv, const ushort* __restrict__ agg,
    float* __restrict__ kv)
{
    const int h = blockIdx.x, b = blockIdx.y, t = threadIdx.x;
    const ushort* src = (h < 32)
        ? qkv + ((size_t)(b * CQKV + h * 24)) * P4096
        : agg + ((size_t)(b * CQKV + (h - 32) * 24)) * P4096;

    float acc[72];
    #pragma unroll
    for (int i = 0; i < 72; i++) acc[i] = 0.0f;

    for (int pi = 0; pi < 16; pi++) {
        int p = t + pi * 256;
        float kvv[8], vv[8];
        #pragma unroll
        for (int d = 0; d < 8; d++) {
            float xk = bf2f(src[(size_t)(8 + d) * P4096 + p]);
            kvv[d] = xk > 0.0f ? xk : 0.0f;
        }
        #pragma unroll
        for (int e = 0; e < 8; e++) vv[e] = bf2f(src[(size_t)(16 + e) * P4096 + p]);
        #pragma unroll
        for (int d = 0; d < 8; d++) {
            #pragma unroll
            for (int e = 0; e < 8; e++) acc[d * 9 + e] += kvv[d] * vv[e];
            acc[d * 9 + 8] += kvv[d];
        }
    }

    #pragma unroll
    for (int i = 0; i < 72; i++) {
        float v = acc[i];
        #pragma unroll
        for (int off = 32; off > 0; off >>= 1) v += __shfl_xor(v, off, 64);
        acc[i] = v;
    }
    __shared__ float part[4][72];
    int wave = t >> 6, lane = t & 63;
    if (lane == 0) {
        #pragma unroll
        for (int i = 0; i < 72; i++) part[wave][i] = acc[i];
    }
    __syncthreads();
    if (t < 72)
        kv[((size_t)b * 64 + h) * 72 + t] = part[0][t] + part[1][t] + part[2][t] + part[3][t];
}

// ---------------- attn: out = (q.kv)_e / ((q.kv)_8 + 1e-15), 2 px/thread ----------------
__global__ __launch_bounds__(256) void attn_out_kernel(
    const float* __restrict__ qplane, ushort* __restrict__ agg,
    const float* __restrict__ kv)
{
    const int pt = blockIdx.x, h = blockIdx.y, b = blockIdx.z, t = threadIdx.x;
    __shared__ float kvs[72];
    if (t < 72) kvs[t] = kv[((size_t)b * 64 + h) * 72 + t];
    __syncthreads();

    const bool lohead = (h < 32);
    const float* srcf = lohead
        ? qplane + ((size_t)(b * 256 + h * 8)) * P4096 : nullptr;
    const ushort* srcb = lohead ? nullptr
        : agg + ((size_t)(b * CQKV + (h - 32) * 24)) * P4096;

    int p = pt * 512 + t * 2;
    float num0[8], num1[8]; float den0 = 0.0f, den1 = 0.0f;
    #pragma unroll
    for (int e = 0; e < 8; e++) { num0[e] = 0.0f; num1[e] = 0.0f; }
    #pragma unroll
    for (int d = 0; d < 8; d++) {
        float q0, q1;
        if (lohead) {
            float2 qq = *(const float2*)(srcf + (size_t)d * P4096 + p);
            q0 = qq.x; q1 = qq.y;
        } else {
            unsigned int u = *(const unsigned int*)(srcb + (size_t)d * P4096 + p);
            q0 = bf2f((ushort)(u & 0xffff)); q1 = bf2f((ushort)(u >> 16));
        }
        q0 = q0 > 0.0f ? q0 : 0.0f;
        q1 = q1 > 0.0f ? q1 : 0.0f;
        #pragma unroll
        for (int e = 0; e < 8; e++) {
            num0[e] += q0 * kvs[d * 9 + e];
            num1[e] += q1 * kvs[d * 9 + e];
        }
        den0 += q0 * kvs[d * 9 + 8];
        den1 += q1 * kvs[d * 9 + 8];
    }
    float rd0 = 1.0f / (den0 + 1e-15f);
    float rd1 = 1.0f / (den1 + 1e-15f);
    ushort* dst = agg + ((size_t)(b * CQKV + (h / 2) * 24 + 8 + (h % 2) * 8)) * P4096 + p;
    #pragma unroll
    for (int e = 0; e < 8; e++) {
        unsigned int u = (unsigned int)f2bf(num0[e] * rd0) |
                         ((unsigned int)f2bf(num1[e] * rd1) << 16);
        *(unsigned int*)(dst + (size_t)e * P4096) = u;
    }
}

// ---------------- GEMM3 v2: y = W_proj @ out, 128x128 tile, dbuf pipeline ----------------
__global__ __launch_bounds__(256, 3) void gemm_proj(
    const ushort* __restrict__ Awp,    // 256x512 bf16 swizzled
    const ushort* __restrict__ Bagg,   // out in agg k/v slots, map(k)=(k/16)*24+8+(k%16)
    float* __restrict__ Y,
    const float* __restrict__ bn_g, const float* __restrict__ bn_b,
    const float* __restrict__ bn_m, const float* __restrict__ bn_v)
{
    const int hw = blockIdx.x;                 // 0..1023
    const int lg = (hw & 7) * 128 + (hw >> 3);
    const int mt = lg & 1;
    const int rem = lg >> 1;                   // 0..511
    const int n0 = (rem & 31) * 128;
    const int b  = rem >> 5;
    const int t  = threadIdx.x;
    const int wave = t >> 6, lane = t & 63, quad = lane >> 4, l15 = lane & 15;
    const int wr = wave >> 1, wc = wave & 1;
    const int M0 = mt * 128;

    __shared__ __align__(16) ushort As[2][4096];   // [128][32]
    __shared__ __align__(16) ushort Bs[2][5120];   // [128][40]

    int aoff[4], boff[4];
    #pragma unroll
    for (int i = 0; i < 4; i++) {
        int ra = wr * 64 + i * 16 + l15;
        aoff[i] = ra * 64 + ((quad ^ ((ra >> 1) & 3)) << 4);   // bytes
        int rb = wc * 64 + i * 16 + l15;
        boff[i] = rb * 80 + quad * 16;                          // bytes, pad-40 rows
    }

    const int arow0 = t >> 2, achk = (t & 3) * 8;
    const size_t abase = (size_t)(M0 + arow0) * 512 + achk;       // i=0
    const size_t abase1 = (size_t)(M0 + 64 + arow0) * 512 + achk; // i=1 (row+64)
    const int ldsoffA = wave * 1024;   // bytes; +4096 for i=1

    const int bn_ = t & 127, half = t >> 7;
    const size_t bchanstride = (size_t)P4096;

    f32x4 acc[4][4];
    #pragma unroll
    for (int mi = 0; mi < 4; mi++)
        #pragma unroll
        for (int nj = 0; nj < 4; nj++)
            #pragma unroll
            for (int r = 0; r < 4; r++) acc[mi][nj][r] = 0.0f;

    auto stageA = [&](int d, int kw) {
        gload16((char*)As[d] + ldsoffA,        Awp + abase  + (size_t)kw * 32);
        gload16((char*)As[d] + ldsoffA + 4096, Awp + abase1 + (size_t)kw * 32);
    };
    ushort bu[16];
    auto loadB = [&](int kw) {
        const ushort* bsrc = Bagg
            + ((size_t)b * CQKV + (size_t)(kw * 2 + half) * 24 + 8) * P4096
            + n0 + bn_;
        #pragma unroll
        for (int j = 0; j < 16; j++) bu[j] = bsrc[(size_t)j * bchanstride];
    };
    auto writeB = [&](int d) {
        union { ushort us[8]; uint4 q; } P0, P1;
        #pragma unroll
        for (int j = 0; j < 8; j++) { P0.us[j] = bu[j]; P1.us[j] = bu[8 + j]; }
        ushort* dst = &Bs[d][bn_ * 40 + half * 16];
        *(uint4*)dst = P0.q;
        *(uint4*)(dst + 8) = P1.q;
    };

    // prologue
    stageA(0, 0);
    loadB(0);
    asm volatile("s_waitcnt vmcnt(0)" ::: "memory");
    writeB(0);
    asm volatile("s_waitcnt lgkmcnt(0)" ::: "memory");
    __builtin_amdgcn_s_barrier();

    for (int kw = 0; kw < 16; kw++) {
        int cur = kw & 1;
        if (kw < 15) {
            stageA(cur ^ 1, kw + 1);
            loadB(kw + 1);
        }
        bf16x8 af[4];
        #pragma unroll
        for (int mi = 0; mi < 4; mi++)
            af[mi] = *(const bf16x8*)((const char*)As[cur] + aoff[mi]);
        #pragma unroll
        for (int nj = 0; nj < 4; nj++) {
            bf16x8 bf = *(const bf16x8*)((const char*)Bs[cur] + boff[nj]);
            #pragma unroll
            for (int mi = 0; mi < 4; mi++)
                acc[mi][nj] = MFMA_BF16(af[mi], bf, acc[mi][nj], 0, 0, 0);
        }
        __builtin_amdgcn_s_barrier();       // all reads of buf[cur] complete
        if (kw < 15) {
            asm volatile("s_waitcnt vmcnt(0)" ::: "memory");  // A(next) in LDS, B(next) regs ready
            writeB(cur ^ 1);
            asm volatile("s_waitcnt lgkmcnt(0)" ::: "memory");
        }
        __builtin_amdgcn_s_barrier();
    }

    #pragma unroll
    for (int mi = 0; mi < 4; mi++)
        #pragma unroll
        for (int nj = 0; nj < 4; nj++)
            #pragma unroll
            for (int r = 0; r < 4; r++) {
                int row = M0 + wr * 64 + mi * 16 + quad * 4 + r;
                int col = n0 + wc * 64 + nj * 16 + l15;
                float inv = bn_g[row] / sqrtf(bn_v[row] + 1e-5f);
                float v = acc[mi][nj][r] * inv + (bn_b[row] - bn_m[row] * inv);
                Y[((size_t)b * 256 + row) * P4096 + col] = v;
            }
}

// ---------------- launch ----------------
extern "C" void kernel_launch(void* const* d_in, const int* in_sizes, int n_in,
                              void* d_out, int out_size, void* d_ws, size_t ws_size,
                              hipStream_t stream) {
    const float* x      = (const float*)d_in[0];
    const float* w_qkv  = (const float*)d_in[1];
    const float* w_dw   = (const float*)d_in[2];
    const float* w_pw   = (const float*)d_in[3];
    const float* w_proj = (const float*)d_in[4];
    const float* bn_g   = (const float*)d_in[5];
    const float* bn_b   = (const float*)d_in[6];
    const float* bn_m   = (const float*)d_in[7];
    const float* bn_v   = (const float*)d_in[8];
    float* y = (float*)d_out;

    char* ws = (char*)d_ws;
    ushort* qkv_bf = (ushort*)(ws);                  // 96 MiB: bf16 768ch
    float*  qplane = (float*) (ws + 100663296);      // 64 MiB: fp32 q (heads 0-31)
    ushort* agg_bf = (ushort*)(ws + 167772160);      // 96 MiB: agg; k/v slots reused for out
    // aliases inside agg region, dead once dwpw runs:
    ushort* XTh = (ushort*)(ws + 167772160);                       // 32 MiB
    ushort* XTl = (ushort*)(ws + 167772160 + 33554432);            // 32 MiB
    ushort* Awh = (ushort*)(ws + 167772160 + 67108864);            // 384 KiB
    ushort* Awl = (ushort*)(ws + 167772160 + 67108864 + 393216);   // 384 KiB
    // alias inside qplane region, dead after attn_out:
    ushort* Awp = (ushort*)(ws + 100663296);                       // 256 KiB
    float*  kvbuf  = (float*)d_out;                  // 288 KB scratch; gemm_proj overwrites
    unsigned int* qmeta = (unsigned int*)((char*)d_out + 524288);  // cnt + 8MB worklist

    conv_wx<<<dim3(4864), 256, 0, stream>>>(x, w_qkv, XTh, XTl, Awh, Awl, qmeta);

    gemm_fused<<<dim3(3072), 256, 0, stream>>>(
        Awh, Awl, XTh, XTl, qkv_bf, qplane, qmeta);

    dwpw_qfix<<<dim3(6400), 512, 0, stream>>>(
        qkv_bf, w_dw, w_pw, agg_bf, qplane, w_qkv, x, qmeta);

    kv_kernel<<<dim3(64, NB), 256, 0, stream>>>(qkv_bf, agg_bf, kvbuf);

    attn_out_kernel<<<dim3(8, 64, NB), 256, 0, stream>>>(qplane, agg_bf, kvbuf);

    conv_wp<<<dim3(256), 256, 0, stream>>>(w_proj, Awp);   // qplane dead now

    gemm_proj<<<dim3(1024), 256, 0, stream>>>(
        Awp, agg_bf, y, bn_g, bn_b, bn_m, bn_v);
}

// Round 14
// 385.388 us; speedup vs baseline: 1.0807x; 1.0076x over previous
//
#include <hip/hip_runtime.h>
#include <hip/hip_bf16.h>

// LiteMSA pipeline, MI355X gfx950.
// B=16, Cin=256, Cqkv=768, H=W=64 (P=4096), heads=64 (24 ch: q8,k8,v8),
// out 512 ch -> proj 256 ch + BN. Output y fp32.
//
// v13 = v10 exact revert (best verified: 384.8us @ R11).
// R12 attn-fusion (-32us) and R13 launch-merges (-3.5us) both reverted.
// Structure: pre-converted bf16 hi/lo inputs (conv_w/conv_x, swizzled);
// gemm_fused 128x128 48KB (q: 3-term split, single-A/double-B; kv: 1-term,
// 3-stage pipeline, counted vmcnt) + sparse qfix worklist -> qfix2 fp64;
// dwpw 16-row bf16 tiles; kv; attn_out 2px/thread; conv_wp; gemm_proj
// 128x128 dbuf issue-early/write-late @ 3 blocks/CU.
//
// ws (256 MiB):
//   qkv_bf [0,96M)    bf16 768ch
//   qplane [96M,160M) fp32 256ch (q of heads 0-31); REUSED after attn_out
//                     for Awp (w_proj bf16 256x512, 256KB)
//   agg_bf [160M,256M) bf16 768ch; ALIASED before dwpw by XTh/XTl/Awh/Awl
// d_out: kvbuf 288K scratch at head; qmeta (cnt + worklist) at +512K.

#define NB 16
#define CQKV 768
#define P4096 4096
#define QFIX_CAP (1u << 21)

typedef __bf16 bf16x8 __attribute__((ext_vector_type(8)));
typedef float f32x4 __attribute__((ext_vector_type(4)));

#define MFMA_BF16 __builtin_amdgcn_mfma_f32_16x16x32_bf16

__device__ __forceinline__ ushort f2bf(float f) {
    union { float f; unsigned int u; } x; x.f = f;
    unsigned int u = x.u;
    unsigned int r = (u + 0x7FFFu + ((u >> 16) & 1u)) >> 16;
    return (ushort)r;
}
__device__ __forceinline__ float bf2f(ushort u) {
    union { unsigned int u; float f; } x; x.u = ((unsigned int)u) << 16;
    return x.f;
}
__device__ __forceinline__ unsigned int pk2bf(float x, float y) {
    __hip_bfloat162 h = __float22bfloat162_rn(make_float2(x, y));  // v_cvt_pk_bf16_f32 (RNE)
    union { __hip_bfloat162 b; unsigned int u; } c; c.b = h; return c.u;
}

__device__ __forceinline__ void gload16(void* lds, const void* g) {
    __builtin_amdgcn_global_load_lds(
        (const __attribute__((address_space(1))) void*)g,
        (__attribute__((address_space(3))) void*)lds, 16, 0, 0);
}

// ---------------- conv_w: w_qkv -> virt-row-ordered, swizzled bf16 hi/lo (+ zero qmeta) ----------------
// virt rows: 0..255 q (phys=(v>>3)*24+v&7), 256..767 kv (phys=(v2>>4)*24+8+v2&15).
__global__ __launch_bounds__(128) void conv_w(
    const float* __restrict__ W, ushort* __restrict__ Ah, ushort* __restrict__ Al,
    unsigned int* __restrict__ qmeta)
{
    const int rv = blockIdx.x;     // 0..767
    const int t  = threadIdx.x;    // 0..127 -> c pair
    if (rv == 0 && t == 0) qmeta[0] = 0;
    int phys;
    if (rv < 256) phys = (rv >> 3) * 24 + (rv & 7);
    else { int r2 = rv - 256; phys = (r2 >> 4) * 24 + 8 + (r2 & 15); }
    int c = t * 2;
    float w0 = W[(size_t)phys * 256 + c];
    float w1 = W[(size_t)phys * 256 + c + 1];
    unsigned int h = pk2bf(w0, w1);
    float f0 = __uint_as_float(h << 16);
    float f1 = __uint_as_float(h & 0xffff0000u);
    unsigned int l = pk2bf(w0 - f0, w1 - f1);
    int sl = ((c >> 3) & 3) ^ ((rv >> 1) & 3);
    int idx = (c & ~31) + sl * 8 + (c & 7);
    *(unsigned int*)&Ah[(size_t)rv * 256 + idx] = h;
    *(unsigned int*)&Al[(size_t)rv * 256 + idx] = l;
}

// ---------------- conv_wp: w_proj 256x512 -> swizzled bf16 ----------------
__global__ __launch_bounds__(256) void conv_wp(
    const float* __restrict__ W, ushort* __restrict__ Awp)
{
    const int m = blockIdx.x;      // 0..255
    const int t = threadIdx.x;     // 0..255 -> c pair
    int c = t * 2;
    float w0 = W[(size_t)m * 512 + c];
    float w1 = W[(size_t)m * 512 + c + 1];
    unsigned int h = pk2bf(w0, w1);
    int sl = ((c >> 3) & 3) ^ ((m >> 1) & 3);
    int idx = (c & ~31) + sl * 8 + (c & 7);
    *(unsigned int*)&Awp[(size_t)m * 512 + idx] = h;
}

// ---------------- conv_x: x [b][256][4096] f32 -> XT hi/lo [b][4096][256] bf16, swizzled ----------------
__global__ __launch_bounds__(256) void conv_x(
    const float* __restrict__ X, ushort* __restrict__ XTh, ushort* __restrict__ XTl)
{
    const int pt = blockIdx.x;        // 0..63
    const int ct = blockIdx.y;        // 0..3
    const int b  = blockIdx.z;
    const int t  = threadIdx.x;
    const int p0 = pt * 64, c0 = ct * 64;

    __shared__ float tile[64][65];

    {
        int cr = t >> 2, pc = (t & 3) * 16;
        const float* xr = X + ((size_t)b * 256 + c0 + cr) * P4096 + p0 + pc;
        float4 v0 = *(const float4*)xr;
        float4 v1 = *(const float4*)(xr + 4);
        float4 v2 = *(const float4*)(xr + 8);
        float4 v3 = *(const float4*)(xr + 12);
        float* d = &tile[cr][pc];
        d[0]=v0.x; d[1]=v0.y; d[2]=v0.z; d[3]=v0.w;
        d[4]=v1.x; d[5]=v1.y; d[6]=v1.z; d[7]=v1.w;
        d[8]=v2.x; d[9]=v2.y; d[10]=v2.z; d[11]=v2.w;
        d[12]=v3.x; d[13]=v3.y; d[14]=v3.z; d[15]=v3.w;
    }
    __syncthreads();

    #pragma unroll
    for (int pass = 0; pass < 2; pass++) {
        int tp = t >> 2;
        int cc = (t & 3) + pass * 4;      // 0..7 chunk of 8 c
        int p  = p0 + tp;
        float v[8];
        #pragma unroll
        for (int j = 0; j < 8; j++) v[j] = tile[cc * 8 + j][tp];
        union { unsigned int u[4]; uint4 q; } H, L;
        #pragma unroll
        for (int i = 0; i < 4; i++) {
            unsigned int h = pk2bf(v[2 * i], v[2 * i + 1]);
            H.u[i] = h;
            float f0 = __uint_as_float(h << 16);
            float f1 = __uint_as_float(h & 0xffff0000u);
            L.u[i] = pk2bf(v[2 * i] - f0, v[2 * i + 1] - f1);
        }
        int c = c0 + cc * 8;
        int sl = ((c >> 3) & 3) ^ ((p >> 1) & 3);
        size_t idx = ((size_t)b * P4096 + p) * 256 + (c & ~31) + sl * 8;
        *(uint4*)&XTh[idx] = H.q;
        *(uint4*)&XTl[idx] = L.q;
    }
}

// ---------------- gemm_fused: all 768 virt rows; q tiles 3-term, kv tiles 1-term ----------------
// 128x128 tile, BK=32, 4 waves (2x2), 48KB LDS -> 3 blocks/CU.
// q branch: A (L2-hot) single-buffered, B double-buffered.
// kv branch: 3-stage pipeline, counted vmcnt(8).
// Grid 3072, XCD swizzle. q epilogue emits sparse qfix worklist.
__global__ __launch_bounds__(256, 3) void gemm_fused(
    const ushort* __restrict__ Ah, const ushort* __restrict__ Al,
    const ushort* __restrict__ Bh, const ushort* __restrict__ Bl,
    ushort* __restrict__ Cbf, float* __restrict__ qplane,
    unsigned int* __restrict__ qmeta)
{
    const int hw = blockIdx.x;                 // 0..3071
    const int lg = (hw & 7) * 384 + (hw >> 3); // XCD-contiguous logical id
    const int mt = lg % 6;
    const int rem = lg / 6;                    // 0..511
    const int n0 = (rem & 31) * 128;
    const int b  = rem >> 5;
    const int t  = threadIdx.x;
    const int wave = t >> 6, lane = t & 63, quad = lane >> 4, l15 = lane & 15;
    const int wr = wave >> 1, wc = wave & 1;
    const int M0 = mt * 128;

    __shared__ __align__(16) char smem[49152];   // 48 KB

    int aoff[4], boff[4];
    #pragma unroll
    for (int i = 0; i < 4; i++) {
        int ra = wr * 64 + i * 16 + l15;
        aoff[i] = ra * 64 + ((quad ^ ((ra >> 1) & 3)) << 4);
        int rb = wc * 64 + i * 16 + l15;
        boff[i] = rb * 64 + ((quad ^ ((rb >> 1) & 3)) << 4);
    }

    const int srow = t >> 2;               // 0..63
    const int schunk = (t & 3) * 8;        // ushort offset in 32-ushort window
    const size_t abase = (size_t)(M0 + srow) * 256 + schunk;
    const size_t bbase = ((size_t)b * P4096 + n0 + srow) * 256 + schunk;
    const int ldsoff = wave * 1024;        // bytes; +i*4096

    f32x4 acc[4][4];
    #pragma unroll
    for (int mi = 0; mi < 4; mi++)
        #pragma unroll
        for (int nj = 0; nj < 4; nj++)
            #pragma unroll
            for (int r = 0; r < 4; r++) acc[mi][nj][r] = 0.0f;

    if (mt < 2) {
        // ---- q rows: 3-term split; single-A (16K) + double-B (32K) ----
        char* AsH = smem;                  // 8K
        char* AsL = smem + 8192;           // 8K
        char* BsH[2] = { smem + 16384, smem + 24576 };
        char* BsL[2] = { smem + 32768, smem + 40960 };

        auto stageA = [&](int kw) {
            #pragma unroll
            for (int i = 0; i < 2; i++) {
                int lo = ldsoff + i * 4096;
                size_t so = (size_t)(i * 64) * 256 + (size_t)kw * 32;
                gload16(AsH + lo, Ah + abase + so);
                gload16(AsL + lo, Al + abase + so);
            }
        };
        auto stageB = [&](int d, int kw) {
            #pragma unroll
            for (int i = 0; i < 2; i++) {
                int lo = ldsoff + i * 4096;
                size_t so = (size_t)(i * 64) * 256 + (size_t)kw * 32;
                gload16(BsH[d] + lo, Bh + bbase + so);
                gload16(BsL[d] + lo, Bl + bbase + so);
            }
        };
        stageA(0); stageB(0, 0);
        for (int kw = 0; kw < 8; kw++) {
            int cur = kw & 1;
            asm volatile("s_waitcnt vmcnt(0)" ::: "memory");   // stage(kw) landed
            __builtin_amdgcn_s_barrier();
            bf16x8 ah[4], al[4];
            #pragma unroll
            for (int mi = 0; mi < 4; mi++) {
                ah[mi] = *(const bf16x8*)(AsH + aoff[mi]);
                al[mi] = *(const bf16x8*)(AsL + aoff[mi]);
            }
            asm volatile("s_waitcnt lgkmcnt(0)" ::: "memory");
            __builtin_amdgcn_sched_barrier(0);
            __builtin_amdgcn_s_barrier();           // all A(kw) reads retired
            if (kw < 7) { stageA(kw + 1); stageB(cur ^ 1, kw + 1); }
            #pragma unroll
            for (int nj = 0; nj < 4; nj++) {
                bf16x8 bh = *(const bf16x8*)(BsH[cur] + boff[nj]);
                bf16x8 bl = *(const bf16x8*)(BsL[cur] + boff[nj]);
                #pragma unroll
                for (int mi = 0; mi < 4; mi++) {
                    acc[mi][nj] = MFMA_BF16(ah[mi], bh, acc[mi][nj], 0, 0, 0);
                    acc[mi][nj] = MFMA_BF16(al[mi], bh, acc[mi][nj], 0, 0, 0);
                    acc[mi][nj] = MFMA_BF16(ah[mi], bl, acc[mi][nj], 0, 0, 0);
                }
            }
        }
        unsigned int* qlist = qmeta + 16;
        #pragma unroll
        for (int mi = 0; mi < 4; mi++)
            #pragma unroll
            for (int nj = 0; nj < 4; nj++)
                #pragma unroll
                for (int r = 0; r < 4; r++) {
                    int rv = M0 + wr * 64 + mi * 16 + quad * 4 + r;
                    int rp = (rv >> 3) * 24 + (rv & 7);
                    int col = n0 + wc * 64 + nj * 16 + l15;
                    float v = acc[mi][nj][r];
                    Cbf[((size_t)b * CQKV + rp) * P4096 + col] = f2bf(v);
                    qplane[((size_t)b * 256 + rv) * P4096 + col] = v;
                    if (fabsf(v) < 1e-4f) {   // sparse qfix worklist (~2.5e-4 hit rate)
                        unsigned int idx = atomicAdd(qmeta, 1u);
                        if (idx < QFIX_CAP)
                            qlist[idx] = (unsigned int)(((b * 256 + rv) << 12) | col);
                    }
                }
    } else {
        // ---- k/v rows: single term; 3-stage pipeline, vmcnt(8) ----
        char* As[3] = { smem, smem + 8192, smem + 16384 };
        char* Bs[3] = { smem + 24576, smem + 32768, smem + 40960 };
        auto stageKV = [&](int d, int kw) {
            #pragma unroll
            for (int i = 0; i < 2; i++) {
                int lo = ldsoff + i * 4096;
                size_t so = (size_t)(i * 64) * 256 + (size_t)kw * 32;
                gload16(As[d] + lo, Ah + abase + so);
                gload16(Bs[d] + lo, Bh + bbase + so);
            }
        };
        stageKV(0, 0);
        stageKV(1, 1);
        #pragma unroll
        for (int kw = 0; kw < 8; kw++) {
            int cur = kw % 3;
            if (kw < 6) {
                stageKV((kw + 2) % 3, kw + 2);
                asm volatile("s_waitcnt vmcnt(8)" ::: "memory");   // stage(kw) landed
            } else if (kw == 6) {
                asm volatile("s_waitcnt vmcnt(4)" ::: "memory");
            } else {
                asm volatile("s_waitcnt vmcnt(0)" ::: "memory");
            }
            __builtin_amdgcn_s_barrier();
            bf16x8 ah[4];
            #pragma unroll
            for (int mi = 0; mi < 4; mi++)
                ah[mi] = *(const bf16x8*)(As[cur] + aoff[mi]);
            #pragma unroll
            for (int nj = 0; nj < 4; nj++) {
                bf16x8 bh = *(const bf16x8*)(Bs[cur] + boff[nj]);
                #pragma unroll
                for (int mi = 0; mi < 4; mi++)
                    acc[mi][nj] = MFMA_BF16(ah[mi], bh, acc[mi][nj], 0, 0, 0);
            }
            __builtin_amdgcn_s_barrier();   // reads of buf[cur] done before overwrite
        }
        #pragma unroll
        for (int mi = 0; mi < 4; mi++)
            #pragma unroll
            for (int nj = 0; nj < 4; nj++)
                #pragma unroll
                for (int r = 0; r < 4; r++) {
                    int rv2 = (M0 - 256) + wr * 64 + mi * 16 + quad * 4 + r;
                    int rp = (rv2 >> 4) * 24 + 8 + (rv2 & 15);
                    int col = n0 + wc * 64 + nj * 16 + l15;
                    Cbf[((size_t)b * CQKV + rp) * P4096 + col] = f2bf(acc[mi][nj][r]);
                }
    }
}

// ---------------- qfix2: sparse fp64 recompute, one wave per worklist entry ----------------
__global__ __launch_bounds__(256) void qfix2_kernel(
    float* __restrict__ qplane, const float* __restrict__ w_qkv,
    const float* __restrict__ x, const unsigned int* __restrict__ qmeta)
{
    unsigned int n = qmeta[0];
    if (n > QFIX_CAP) n = QFIX_CAP;
    const unsigned int* list = qmeta + 16;
    const int wave = threadIdx.x >> 6, lane = threadIdx.x & 63;
    for (unsigned int e = blockIdx.x * 4 + wave; e < n; e += gridDim.x * 4) {
        unsigned int i = list[e];
        int p   = (int)(i & 4095);
        int qch = (int)((i >> 12) & 255);
        int b   = (int)(i >> 20);
        int row = (qch >> 3) * 24 + (qch & 7);
        const float* wr = w_qkv + (size_t)row * 256;
        const float* xr = x + (size_t)b * 256 * P4096 + p;
        double s = 0.0;
        #pragma unroll
        for (int j = 0; j < 4; j++) {
            int c = lane * 4 + j;
            s += (double)wr[c] * (double)xr[(size_t)c * P4096];
        }
        #pragma unroll
        for (int off = 32; off > 0; off >>= 1) s += __shfl_xor(s, off, 64);
        if (lane == 0)
            qplane[((size_t)(b * 256 + qch)) * P4096 + p] = (float)s;
    }
}

// ---------------- dw 3x3 + grouped pw (bf16; feeds only heads 32-63) ----------------
__global__ __launch_bounds__(512, 8) void dwpw_kernel(
    const ushort* __restrict__ qkv, const float* __restrict__ wdw,
    const float* __restrict__ wpw, ushort* __restrict__ agg)
{
    const int rt = blockIdx.x;    // 0..3 (16 output rows each)
    const int g  = blockIdx.y;    // 0..95
    const int b  = blockIdx.z;
    const int t  = threadIdx.x;   // 0..511
    const int r0 = rt * 16;
    const int cg = g * 8;

    __shared__ __align__(16) ushort tile[8][18][80];   // 23040 B

    const ushort* src = qkv + ((size_t)(b * CQKV + cg)) * P4096;

    if (t < 288) {
        int ch = t / 36;
        int rr = (t % 36) >> 1;
        int side = t & 1;
        *(uint4*)&tile[ch][rr][side * 72] = make_uint4(0, 0, 0, 0);
    }
    #pragma unroll
    for (int i = 0; i < 3; i++) {
        int id = t + i * 512;
        if (id < 1152) {
            int ch  = id / 144;
            int rem = id - ch * 144;
            int rr  = rem >> 3;
            int oct = (rem & 7) * 8;
            int grow = r0 - 1 + rr;
            uint4 v = make_uint4(0, 0, 0, 0);
            if (grow >= 0 && grow < 64)
                v = *(const uint4*)(src + (size_t)ch * P4096 + (size_t)grow * 64 + oct);
            *(uint4*)&tile[ch][rr][8 + oct] = v;
        }
    }
    __syncthreads();

    const int kc  = t & 31;        // col pair: cols 2kc, 2kc+1
    const int row = t >> 5;        // 0..15
    const float* wdwg = wdw + (size_t)cg * 9;   // block-uniform -> s_load
    const float* wpwg = wpw + (size_t)cg * 8;

    float acc0[8], acc1[8];
    #pragma unroll
    for (int oi = 0; oi < 8; oi++) { acc0[oi] = 0.0f; acc1[oi] = 0.0f; }

    #pragma unroll
    for (int c = 0; c < 8; c++) {
        float dv0 = 0.0f, dv1 = 0.0f;
        #pragma unroll
        for (int dy = 0; dy < 3; dy++) {
            const ushort* rp = &tile[c][row + dy][2 * kc + 4];
            unsigned int u1 = *(const unsigned int*)(rp + 2);
            unsigned int u2 = *(const unsigned int*)(rp + 4);
            unsigned int u3 = *(const unsigned int*)(rp + 6);
            float xm1 = __uint_as_float(u1 & 0xffff0000u);
            float x0  = __uint_as_float(u2 << 16);
            float x1  = __uint_as_float(u2 & 0xffff0000u);
            float x2  = __uint_as_float(u3 << 16);
            float w0 = wdwg[c * 9 + dy * 3 + 0];
            float w1 = wdwg[c * 9 + dy * 3 + 1];
            float w2 = wdwg[c * 9 + dy * 3 + 2];
            dv0 = fmaf(w0, xm1, dv0); dv0 = fmaf(w1, x0, dv0); dv0 = fmaf(w2, x1, dv0);
            dv1 = fmaf(w0, x0,  dv1); dv1 = fmaf(w1, x1, dv1); dv1 = fmaf(w2, x2, dv1);
        }
        #pragma unroll
        for (int oi = 0; oi < 8; oi++) {
            float w = wpwg[oi * 8 + c];
            acc0[oi] = fmaf(w, dv0, acc0[oi]);
            acc1[oi] = fmaf(w, dv1, acc1[oi]);
        }
    }

    size_t obase = ((size_t)(b * CQKV + cg)) * P4096 + (size_t)(r0 + row) * 64 + 2 * kc;
    #pragma unroll
    for (int oi = 0; oi < 8; oi++) {
        unsigned int u = (unsigned int)f2bf(acc0[oi]) |
                         ((unsigned int)f2bf(acc1[oi]) << 16);
        *(unsigned int*)&agg[obase + (size_t)oi * P4096] = u;
    }
}

// ---------------- kv[b,h,d,e] = sum_p relu(k_d)*v_e  (v_8 = 1) ----------------
__global__ __launch_bounds__(256) void kv_kernel(
    const ushort* __restrict__ qkv, const ushort* __restrict__ agg,
    float* __restrict__ kv)
{
    const int h = blockIdx.x, b = blockIdx.y, t = threadIdx.x;
    const ushort* src = (h < 32)
        ? qkv + ((size_t)(b * CQKV + h * 24)) * P4096
        : agg + ((size_t)(b * CQKV + (h - 32) * 24)) * P4096;

    float acc[72];
    #pragma unroll
    for (int i = 0; i < 72; i++) acc[i] = 0.0f;

    for (int pi = 0; pi < 16; pi++) {
        int p = t + pi * 256;
        float kvv[8], vv[8];
        #pragma unroll
        for (int d = 0; d < 8; d++) {
            float xk = bf2f(src[(size_t)(8 + d) * P4096 + p]);
            kvv[d] = xk > 0.0f ? xk : 0.0f;
        }
        #pragma unroll
        for (int e = 0; e < 8; e++) vv[e] = bf2f(src[(size_t)(16 + e) * P4096 + p]);
        #pragma unroll
        for (int d = 0; d < 8; d++) {
            #pragma unroll
            for (int e = 0; e < 8; e++) acc[d * 9 + e] += kvv[d] * vv[e];
            acc[d * 9 + 8] += kvv[d];
        }
    }

    #pragma unroll
    for (int i = 0; i < 72; i++) {
        float v = acc[i];
        #pragma unroll
        for (int off = 32; off > 0; off >>= 1) v += __shfl_xor(v, off, 64);
        acc[i] = v;
    }
    __shared__ float part[4][72];
    int wave = t >> 6, lane = t & 63;
    if (lane == 0) {
        #pragma unroll
        for (int i = 0; i < 72; i++) part[wave][i] = acc[i];
    }
    __syncthreads();
    if (t < 72)
        kv[((size_t)b * 64 + h) * 72 + t] = part[0][t] + part[1][t] + part[2][t] + part[3][t];
}

// ---------------- attn: out = (q.kv)_e / ((q.kv)_8 + 1e-15), 2 px/thread ----------------
__global__ __launch_bounds__(256) void attn_out_kernel(
    const float* __restrict__ qplane, ushort* __restrict__ agg,
    const float* __restrict__ kv)
{
    const int pt = blockIdx.x, h = blockIdx.y, b = blockIdx.z, t = threadIdx.x;
    __shared__ float kvs[72];
    if (t < 72) kvs[t] = kv[((size_t)b * 64 + h) * 72 + t];
    __syncthreads();

    const bool lohead = (h < 32);
    const float* srcf = lohead
        ? qplane + ((size_t)(b * 256 + h * 8)) * P4096 : nullptr;
    const ushort* srcb = lohead ? nullptr
        : agg + ((size_t)(b * CQKV + (h - 32) * 24)) * P4096;

    int p = pt * 512 + t * 2;
    float num0[8], num1[8]; float den0 = 0.0f, den1 = 0.0f;
    #pragma unroll
    for (int e = 0; e < 8; e++) { num0[e] = 0.0f; num1[e] = 0.0f; }
    #pragma unroll
    for (int d = 0; d < 8; d++) {
        float q0, q1;
        if (lohead) {
            float2 qq = *(const float2*)(srcf + (size_t)d * P4096 + p);
            q0 = qq.x; q1 = qq.y;
        } else {
            unsigned int u = *(const unsigned int*)(srcb + (size_t)d * P4096 + p);
            q0 = bf2f((ushort)(u & 0xffff)); q1 = bf2f((ushort)(u >> 16));
        }
        q0 = q0 > 0.0f ? q0 : 0.0f;
        q1 = q1 > 0.0f ? q1 : 0.0f;
        #pragma unroll
        for (int e = 0; e < 8; e++) {
            num0[e] += q0 * kvs[d * 9 + e];
            num1[e] += q1 * kvs[d * 9 + e];
        }
        den0 += q0 * kvs[d * 9 + 8];
        den1 += q1 * kvs[d * 9 + 8];
    }
    float rd0 = 1.0f / (den0 + 1e-15f);
    float rd1 = 1.0f / (den1 + 1e-15f);
    ushort* dst = agg + ((size_t)(b * CQKV + (h / 2) * 24 + 8 + (h % 2) * 8)) * P4096 + p;
    #pragma unroll
    for (int e = 0; e < 8; e++) {
        unsigned int u = (unsigned int)f2bf(num0[e] * rd0) |
                         ((unsigned int)f2bf(num1[e] * rd1) << 16);
        *(unsigned int*)(dst + (size_t)e * P4096) = u;
    }
}

// ---------------- GEMM3 v2: y = W_proj @ out, 128x128 tile, dbuf pipeline ----------------
__global__ __launch_bounds__(256, 3) void gemm_proj(
    const ushort* __restrict__ Awp,    // 256x512 bf16 swizzled
    const ushort* __restrict__ Bagg,   // out in agg k/v slots, map(k)=(k/16)*24+8+(k%16)
    float* __restrict__ Y,
    const float* __restrict__ bn_g, const float* __restrict__ bn_b,
    const float* __restrict__ bn_m, const float* __restrict__ bn_v)
{
    const int hw = blockIdx.x;                 // 0..1023
    const int lg = (hw & 7) * 128 + (hw >> 3);
    const int mt = lg & 1;
    const int rem = lg >> 1;                   // 0..511
    const int n0 = (rem & 31) * 128;
    const int b  = rem >> 5;
    const int t  = threadIdx.x;
    const int wave = t >> 6, lane = t & 63, quad = lane >> 4, l15 = lane & 15;
    const int wr = wave >> 1, wc = wave & 1;
    const int M0 = mt * 128;

    __shared__ __align__(16) ushort As[2][4096];   // [128][32]
    __shared__ __align__(16) ushort Bs[2][5120];   // [128][40]

    int aoff[4], boff[4];
    #pragma unroll
    for (int i = 0; i < 4; i++) {
        int ra = wr * 64 + i * 16 + l15;
        aoff[i] = ra * 64 + ((quad ^ ((ra >> 1) & 3)) << 4);   // bytes
        int rb = wc * 64 + i * 16 + l15;
        boff[i] = rb * 80 + quad * 16;                          // bytes, pad-40 rows
    }

    const int arow0 = t >> 2, achk = (t & 3) * 8;
    const size_t abase = (size_t)(M0 + arow0) * 512 + achk;       // i=0
    const size_t abase1 = (size_t)(M0 + 64 + arow0) * 512 + achk; // i=1 (row+64)
    const int ldsoffA = wave * 1024;   // bytes; +4096 for i=1

    const int bn_ = t & 127, half = t >> 7;
    const size_t bchanstride = (size_t)P4096;

    f32x4 acc[4][4];
    #pragma unroll
    for (int mi = 0; mi < 4; mi++)
        #pragma unroll
        for (int nj = 0; nj < 4; nj++)
            #pragma unroll
            for (int r = 0; r < 4; r++) acc[mi][nj][r] = 0.0f;

    auto stageA = [&](int d, int kw) {
        gload16((char*)As[d] + ldsoffA,        Awp + abase  + (size_t)kw * 32);
        gload16((char*)As[d] + ldsoffA + 4096, Awp + abase1 + (size_t)kw * 32);
    };
    ushort bu[16];
    auto loadB = [&](int kw) {
        const ushort* bsrc = Bagg
            + ((size_t)b * CQKV + (size_t)(kw * 2 + half) * 24 + 8) * P4096
            + n0 + bn_;
        #pragma unroll
        for (int j = 0; j < 16; j++) bu[j] = bsrc[(size_t)j * bchanstride];
    };
    auto writeB = [&](int d) {
        union { ushort us[8]; uint4 q; } P0, P1;
        #pragma unroll
        for (int j = 0; j < 8; j++) { P0.us[j] = bu[j]; P1.us[j] = bu[8 + j]; }
        ushort* dst = &Bs[d][bn_ * 40 + half * 16];
        *(uint4*)dst = P0.q;
        *(uint4*)(dst + 8) = P1.q;
    };

    // prologue
    stageA(0, 0);
    loadB(0);
    asm volatile("s_waitcnt vmcnt(0)" ::: "memory");
    writeB(0);
    asm volatile("s_waitcnt lgkmcnt(0)" ::: "memory");
    __builtin_amdgcn_s_barrier();

    for (int kw = 0; kw < 16; kw++) {
        int cur = kw & 1;
        if (kw < 15) {
            stageA(cur ^ 1, kw + 1);
            loadB(kw + 1);
        }
        bf16x8 af[4];
        #pragma unroll
        for (int mi = 0; mi < 4; mi++)
            af[mi] = *(const bf16x8*)((const char*)As[cur] + aoff[mi]);
        #pragma unroll
        for (int nj = 0; nj < 4; nj++) {
            bf16x8 bf = *(const bf16x8*)((const char*)Bs[cur] + boff[nj]);
            #pragma unroll
            for (int mi = 0; mi < 4; mi++)
                acc[mi][nj] = MFMA_BF16(af[mi], bf, acc[mi][nj], 0, 0, 0);
        }
        __builtin_amdgcn_s_barrier();       // all reads of buf[cur] complete
        if (kw < 15) {
            asm volatile("s_waitcnt vmcnt(0)" ::: "memory");  // A(next) in LDS, B(next) regs ready
            writeB(cur ^ 1);
            asm volatile("s_waitcnt lgkmcnt(0)" ::: "memory");
        }
        __builtin_amdgcn_s_barrier();
    }

    #pragma unroll
    for (int mi = 0; mi < 4; mi++)
        #pragma unroll
        for (int nj = 0; nj < 4; nj++)
            #pragma unroll
            for (int r = 0; r < 4; r++) {
                int row = M0 + wr * 64 + mi * 16 + quad * 4 + r;
                int col = n0 + wc * 64 + nj * 16 + l15;
                float inv = bn_g[row] / sqrtf(bn_v[row] + 1e-5f);
                float v = acc[mi][nj][r] * inv + (bn_b[row] - bn_m[row] * inv);
                Y[((size_t)b * 256 + row) * P4096 + col] = v;
            }
}

// ---------------- launch ----------------
extern "C" void kernel_launch(void* const* d_in, const int* in_sizes, int n_in,
                              void* d_out, int out_size, void* d_ws, size_t ws_size,
                              hipStream_t stream) {
    const float* x      = (const float*)d_in[0];
    const float* w_qkv  = (const float*)d_in[1];
    const float* w_dw   = (const float*)d_in[2];
    const float* w_pw   = (const float*)d_in[3];
    const float* w_proj = (const float*)d_in[4];
    const float* bn_g   = (const float*)d_in[5];
    const float* bn_b   = (const float*)d_in[6];
    const float* bn_m   = (const float*)d_in[7];
    const float* bn_v   = (const float*)d_in[8];
    float* y = (float*)d_out;

    char* ws = (char*)d_ws;
    ushort* qkv_bf = (ushort*)(ws);                  // 96 MiB: bf16 768ch
    float*  qplane = (float*) (ws + 100663296);      // 64 MiB: fp32 q (heads 0-31)
    ushort* agg_bf = (ushort*)(ws + 167772160);      // 96 MiB: agg; k/v slots reused for out
    // aliases inside agg region, dead once dwpw runs:
    ushort* XTh = (ushort*)(ws + 167772160);                       // 32 MiB
    ushort* XTl = (ushort*)(ws + 167772160 + 33554432);            // 32 MiB
    ushort* Awh = (ushort*)(ws + 167772160 + 67108864);            // 384 KiB
    ushort* Awl = (ushort*)(ws + 167772160 + 67108864 + 393216);   // 384 KiB
    // alias inside qplane region, dead after attn_out:
    ushort* Awp = (ushort*)(ws + 100663296);                       // 256 KiB
    float*  kvbuf  = (float*)d_out;                  // 288 KB scratch; gemm_proj overwrites
    unsigned int* qmeta = (unsigned int*)((char*)d_out + 524288);  // cnt + 8MB worklist

    conv_w<<<dim3(768), 128, 0, stream>>>(w_qkv, Awh, Awl, qmeta);
    conv_x<<<dim3(64, 4, NB), 256, 0, stream>>>(x, XTh, XTl);

    gemm_fused<<<dim3(3072), 256, 0, stream>>>(
        Awh, Awl, XTh, XTl, qkv_bf, qplane, qmeta);

    qfix2_kernel<<<dim3(1024), 256, 0, stream>>>(qplane, w_qkv, x, qmeta);

    dwpw_kernel<<<dim3(4, 96, NB), 512, 0, stream>>>(qkv_bf, w_dw, w_pw, agg_bf);

    kv_kernel<<<dim3(64, NB), 256, 0, stream>>>(qkv_bf, agg_bf, kvbuf);

    attn_out_kernel<<<dim3(8, 64, NB), 256, 0, stream>>>(qplane, agg_bf, kvbuf);

    conv_wp<<<dim3(256), 256, 0, stream>>>(w_proj, Awp);   // qplane dead now

    gemm_proj<<<dim3(1024), 256, 0, stream>>>(
        Awp, agg_bf, y, bn_g, bn_b, bn_m, bn_v);
}